// Round 1
// baseline (411.074 us; speedup 1.0000x reference)
//
#include <hip/hip_runtime.h>

#define E 128
#define HEAD_W 138      // E + 2 + 2*(2+2) = 138
#define OFF_Q 128
#define OFF_HEAD 256
#define OFF_REL 394
#define OFF_TAIL 522
#define TN 16

__global__ void count_kernel(const int* __restrict__ h_id, const int* __restrict__ t_id,
                             unsigned* cnt_rev, unsigned* cnt_fwd, int T) {
    int e = blockIdx.x * blockDim.x + threadIdx.x;
    if (e < T) {
        atomicAdd(&cnt_fwd[t_id[e]], 1u);
        atomicAdd(&cnt_rev[h_id[e]], 1u);
    }
}

__global__ void inv_kernel(const unsigned* __restrict__ cnt_fwd, const unsigned* __restrict__ cnt_rev,
                           float* __restrict__ inv_fwd, float* __restrict__ inv_rev, int N) {
    int n = blockIdx.x * blockDim.x + threadIdx.x;
    if (n < N) {
        unsigned cf = cnt_fwd[n], cr = cnt_rev[n];
        inv_fwd[n] = 1.0f / (float)(cf > 1u ? cf : 1u);
        inv_rev[n] = 1.0f / (float)(cr > 1u ? cr : 1u);
    }
}

__global__ void scatter_kernel(const int* __restrict__ src, const int* __restrict__ dst,
                               const float* __restrict__ x, float* __restrict__ out, int T) {
    int e = blockIdx.x * blockDim.x + threadIdx.x;
    if (e < T) {
        int s = src[e], d = dst[e];
        atomicAdd(&out[2 * d + 0], x[2 * s + 0]);
        atomicAdd(&out[2 * d + 1], x[2 * s + 1]);
    }
}

__global__ void scale_kernel(float* __restrict__ buf, const float* __restrict__ inv, int N) {
    int n = blockIdx.x * blockDim.x + threadIdx.x;
    if (n < N) {
        float iv = inv[n];
        buf[2 * n + 0] *= iv;
        buf[2 * n + 1] *= iv;
    }
}

// bias3[i][j] = b1[j] + sum_k intent[i][k]*W1[k][j] + sum_k q[k]*W1[128+k][j]
__global__ void bias_kernel(const float* __restrict__ intent, const float* __restrict__ q,
                            const float* __restrict__ W1, const float* __restrict__ b1,
                            float* __restrict__ bias3) {
    int i = blockIdx.x;
    int j = threadIdx.x;
    float acc = b1[j];
    for (int k = 0; k < E; ++k) acc += intent[i * E + k] * W1[k * E + j];
    for (int k = 0; k < E; ++k) acc += q[k] * W1[(OFF_Q + k) * E + j];
    bias3[i * E + j] = acc;
}

// rel_pre[r][j] = sum_k rel[r][k] * W1[OFF_REL+k][j]
__global__ void relpre_kernel(const float* __restrict__ rel, const float* __restrict__ W1,
                              float* __restrict__ rel_pre) {
    int r = blockIdx.x;
    int j = threadIdx.x;
    __shared__ float xs[E];
    xs[j] = rel[r * E + j];
    __syncthreads();
    float acc = 0.f;
    for (int k = 0; k < E; ++k) acc += xs[k] * W1[(OFF_REL + k) * E + j];
    rel_pre[r * E + j] = acc;
}

// head_pre[n][j] = sum_k he[n][k]*W1[OFF_HEAD+k][j]; tail_pre same with OFF_TAIL
// he[n] = [h_e0[n] (128), topic(2), f1(2), f2(2), r1(2), r2(2)]
__global__ __launch_bounds__(E) void nodepre_kernel(
        const float* __restrict__ ent, const float* __restrict__ nontext,
        const float* __restrict__ topic, const float* __restrict__ f1,
        const float* __restrict__ f2, const float* __restrict__ r1,
        const float* __restrict__ r2, const float* __restrict__ W1,
        float* __restrict__ head_pre, float* __restrict__ tail_pre, int N, int NTEXT) {
    __shared__ float Xs[TN][HEAD_W];
    int j = threadIdx.x;  // 0..127
    int ntiles = (N + TN - 1) / TN;
    for (int tile = blockIdx.x; tile < ntiles; tile += gridDim.x) {
        int n0 = tile * TN;
        for (int n = 0; n < TN; ++n) {
            int node = n0 + n;
            Xs[n][j] = (node < N) ? ((node < NTEXT) ? ent[(size_t)node * E + j] : nontext[j]) : 0.f;
        }
        if (j < 10) {
            int m = j;
            const float* src = (m < 2) ? topic : (m < 4) ? f1 : (m < 6) ? f2 : (m < 8) ? r1 : r2;
            int c = m & 1;
            for (int n = 0; n < TN; ++n) {
                int node = n0 + n;
                Xs[n][E + m] = (node < N) ? src[node * 2 + c] : 0.f;
            }
        }
        __syncthreads();
        float acch[TN], acct[TN];
#pragma unroll
        for (int n = 0; n < TN; ++n) { acch[n] = 0.f; acct[n] = 0.f; }
        for (int k = 0; k < HEAD_W; ++k) {
            float wh = W1[(OFF_HEAD + k) * E + j];
            float wt = W1[(OFF_TAIL + k) * E + j];
#pragma unroll
            for (int n = 0; n < TN; ++n) {
                float xv = Xs[n][k];
                acch[n] += xv * wh;
                acct[n] += xv * wt;
            }
        }
        for (int n = 0; n < TN; ++n) {
            int node = n0 + n;
            if (node < N) {
                head_pre[(size_t)node * E + j] = acch[n];
                tail_pre[(size_t)node * E + j] = acct[n];
            }
        }
        __syncthreads();
    }
}

// one wave per edge; lane l owns cols 2l, 2l+1
__global__ __launch_bounds__(256) void edge_kernel(
        const int* __restrict__ h_id, const int* __restrict__ r_id, const int* __restrict__ t_id,
        const float* __restrict__ head_pre, const float* __restrict__ rel_pre,
        const float* __restrict__ tail_pre, const float* __restrict__ bias3,
        const float* __restrict__ W2, const float* __restrict__ b2,
        float* __restrict__ out, int T) {
    int lane = threadIdx.x & 63;
    int wave = blockIdx.x * (blockDim.x >> 6) + (threadIdx.x >> 6);
    int nwaves = gridDim.x * (blockDim.x >> 6);
    int c0 = lane * 2;
    float2 bi0 = *(const float2*)&bias3[0 * E + c0];
    float2 bi1 = *(const float2*)&bias3[1 * E + c0];
    float2 bi2 = *(const float2*)&bias3[2 * E + c0];
    float2 w2 = *(const float2*)&W2[c0];
    float b2s = b2[0];
    for (int e = wave; e < T; e += nwaves) {
        int h = h_id[e], r = r_id[e], t = t_id[e];
        float2 hp = *(const float2*)&head_pre[(size_t)h * E + c0];
        float2 rp = *(const float2*)&rel_pre[(size_t)r * E + c0];
        float2 tp = *(const float2*)&tail_pre[(size_t)t * E + c0];
        float bx = hp.x + rp.x + tp.x;
        float by = hp.y + rp.y + tp.y;
        float p0 = fmaxf(bx + bi0.x, 0.f) * w2.x + fmaxf(by + bi0.y, 0.f) * w2.y;
        float p1 = fmaxf(bx + bi1.x, 0.f) * w2.x + fmaxf(by + bi1.y, 0.f) * w2.y;
        float p2 = fmaxf(bx + bi2.x, 0.f) * w2.x + fmaxf(by + bi2.y, 0.f) * w2.y;
#pragma unroll
        for (int o = 32; o > 0; o >>= 1) {
            p0 += __shfl_xor(p0, o, 64);
            p1 += __shfl_xor(p1, o, 64);
            p2 += __shfl_xor(p2, o, 64);
        }
        if (lane < 3) {
            float v = (lane == 0) ? p0 : ((lane == 1) ? p1 : p2);
            out[(size_t)e * 3 + lane] = v + b2s;
        }
    }
}

extern "C" void kernel_launch(void* const* d_in, const int* in_sizes, int n_in,
                              void* d_out, int out_size, void* d_ws, size_t ws_size,
                              hipStream_t stream) {
    const int* h_id = (const int*)d_in[0];
    const int* r_id = (const int*)d_in[1];
    const int* t_id = (const int*)d_in[2];
    const float* q = (const float*)d_in[3];
    const float* ent = (const float*)d_in[4];
    const float* rel = (const float*)d_in[6];
    const float* topic = (const float*)d_in[7];
    const float* nontext = (const float*)d_in[8];
    const float* intent = (const float*)d_in[9];
    const float* W1 = (const float*)d_in[10];
    const float* b1 = (const float*)d_in[11];
    const float* W2 = (const float*)d_in[12];
    const float* b2 = (const float*)d_in[13];

    int T = in_sizes[0];
    int NTEXT = in_sizes[4] / E;
    int N = in_sizes[7] / 2;
    int NREL = in_sizes[6] / E;

    float* ws = (float*)d_ws;
    unsigned* cnt_fwd = (unsigned*)ws;          // N
    unsigned* cnt_rev = cnt_fwd + N;            // N
    float* inv_fwd = ws + 2 * (size_t)N;        // N
    float* inv_rev = ws + 3 * (size_t)N;        // N
    float* pef1 = ws + 4 * (size_t)N;           // 2N
    float* pef2 = ws + 6 * (size_t)N;           // 2N
    float* per1 = ws + 8 * (size_t)N;           // 2N
    float* per2 = ws + 10 * (size_t)N;          // 2N
    float* bias3 = ws + 12 * (size_t)N;         // 3*E
    float* rel_pre = bias3 + 3 * E;             // NREL*E
    float* head_pre = rel_pre + (size_t)NREL * E;       // N*E
    float* tail_pre = head_pre + (size_t)N * E;         // N*E

    // zero counters + pe scatter buffers (first 12N floats)
    hipMemsetAsync(ws, 0, sizeof(float) * 12 * (size_t)N, stream);

    const int tb = 256;
    int gT = (T + tb - 1) / tb;
    int gN = (N + tb - 1) / tb;

    count_kernel<<<gT, tb, 0, stream>>>(h_id, t_id, cnt_rev, cnt_fwd, T);
    inv_kernel<<<gN, tb, 0, stream>>>(cnt_fwd, cnt_rev, inv_fwd, inv_rev, N);

    scatter_kernel<<<gT, tb, 0, stream>>>(h_id, t_id, topic, pef1, T);
    scale_kernel<<<gN, tb, 0, stream>>>(pef1, inv_fwd, N);
    scatter_kernel<<<gT, tb, 0, stream>>>(h_id, t_id, pef1, pef2, T);
    scale_kernel<<<gN, tb, 0, stream>>>(pef2, inv_fwd, N);
    scatter_kernel<<<gT, tb, 0, stream>>>(t_id, h_id, topic, per1, T);
    scale_kernel<<<gN, tb, 0, stream>>>(per1, inv_rev, N);
    scatter_kernel<<<gT, tb, 0, stream>>>(t_id, h_id, per1, per2, T);
    scale_kernel<<<gN, tb, 0, stream>>>(per2, inv_rev, N);

    bias_kernel<<<3, E, 0, stream>>>(intent, q, W1, b1, bias3);
    relpre_kernel<<<NREL, E, 0, stream>>>(rel, W1, rel_pre);
    nodepre_kernel<<<640, E, 0, stream>>>(ent, nontext, topic, pef1, pef2, per1, per2,
                                          W1, head_pre, tail_pre, N, NTEXT);
    edge_kernel<<<2048, 256, 0, stream>>>(h_id, r_id, t_id, head_pre, rel_pre, tail_pre,
                                          bias3, W2, b2, (float*)d_out, T);
}

// Round 2
// 293.309 us; speedup vs baseline: 1.4015x; 1.4015x over previous
//
#include <hip/hip_runtime.h>

#define E 128
#define OFF_Q 128
#define OFF_HEAD 256
#define OFF_REL 394
#define OFF_TAIL 522
#define KTOT 138      // 128 + 2 + 2*4
#define BM 64
#define XST 68        // padded LDS row stride (words): 4-aligned, bank stride 4

// ---- fused count + first scatter (both directions) ----
__global__ __launch_bounds__(256) void cs1_kernel(
        const int* __restrict__ h_id, const int* __restrict__ t_id,
        const float* __restrict__ topic,
        unsigned* __restrict__ cnt_fwd, unsigned* __restrict__ cnt_rev,
        float* __restrict__ pef1, float* __restrict__ per1, int T) {
    int e = blockIdx.x * blockDim.x + threadIdx.x;
    if (e < T) {
        int h = h_id[e], t = t_id[e];
        atomicAdd(&cnt_fwd[t], 1u);
        atomicAdd(&cnt_rev[h], 1u);
        float2 th = *(const float2*)&topic[2 * (size_t)h];
        float2 tt = *(const float2*)&topic[2 * (size_t)t];
        atomicAdd(&pef1[2 * t + 0], th.x);
        atomicAdd(&pef1[2 * t + 1], th.y);
        atomicAdd(&per1[2 * h + 0], tt.x);
        atomicAdd(&per1[2 * h + 1], tt.y);
    }
}

// ---- scale both buffers by 1/max(cnt,1) ----
__global__ __launch_bounds__(256) void scale_kernel(
        const unsigned* __restrict__ cnt_fwd, const unsigned* __restrict__ cnt_rev,
        float* __restrict__ bf, float* __restrict__ br, int N) {
    int n = blockIdx.x * blockDim.x + threadIdx.x;
    if (n < N) {
        float invf = 1.0f / fmaxf((float)cnt_fwd[n], 1.0f);
        float invr = 1.0f / fmaxf((float)cnt_rev[n], 1.0f);
        bf[2 * n + 0] *= invf;
        bf[2 * n + 1] *= invf;
        br[2 * n + 0] *= invr;
        br[2 * n + 1] *= invr;
    }
}

// ---- second scatter (both directions) ----
__global__ __launch_bounds__(256) void sc2_kernel(
        const int* __restrict__ h_id, const int* __restrict__ t_id,
        const float* __restrict__ pef1, const float* __restrict__ per1,
        float* __restrict__ pef2, float* __restrict__ per2, int T) {
    int e = blockIdx.x * blockDim.x + threadIdx.x;
    if (e < T) {
        int h = h_id[e], t = t_id[e];
        float2 xf = *(const float2*)&pef1[2 * (size_t)h];
        float2 xr = *(const float2*)&per1[2 * (size_t)t];
        atomicAdd(&pef2[2 * t + 0], xf.x);
        atomicAdd(&pef2[2 * t + 1], xf.y);
        atomicAdd(&per2[2 * h + 0], xr.x);
        atomicAdd(&per2[2 * h + 1], xr.y);
    }
}

// bias3[i][j] = b1[j] + intent[i]·W1[0:128][j] + q·W1[128:256][j]
__global__ void bias_kernel(const float* __restrict__ intent, const float* __restrict__ q,
                            const float* __restrict__ W1, const float* __restrict__ b1,
                            float* __restrict__ bias3) {
    int i = blockIdx.x;
    int j = threadIdx.x;
    float acc = b1[j];
#pragma unroll 4
    for (int k = 0; k < E; ++k) acc += intent[i * E + k] * W1[k * E + j];
#pragma unroll 4
    for (int k = 0; k < E; ++k) acc += q[k] * W1[(OFF_Q + k) * E + j];
    bias3[i * E + j] = acc;
}

// rel_pre[r][j] = rel[r]·W1[OFF_REL:OFF_REL+128][j], thread-per-output
__global__ __launch_bounds__(256) void relpre_kernel(
        const float* __restrict__ rel, const float* __restrict__ W1,
        float* __restrict__ rel_pre, int NREL) {
    int idx = blockIdx.x * blockDim.x + threadIdx.x;
    int r = idx >> 7, j = idx & 127;
    if (r >= NREL) return;
    const float4* xr = (const float4*)(rel + (size_t)r * E);
    float acc = 0.f;
#pragma unroll
    for (int k4 = 0; k4 < 32; ++k4) {
        float4 x = xr[k4];
        int k = OFF_REL + k4 * 4;
        acc = fmaf(x.x, W1[(k + 0) * E + j], acc);
        acc = fmaf(x.y, W1[(k + 1) * E + j], acc);
        acc = fmaf(x.z, W1[(k + 2) * E + j], acc);
        acc = fmaf(x.w, W1[(k + 3) * E + j], acc);
    }
    rel_pre[idx] = acc;
}

// head_pre / tail_pre: register-tiled GEMM  [N x 138] @ [138 x 256]
// block: 64 nodes x 256 cols (head 128 | tail 128), 256 threads, 8x8 acc each
__global__ __launch_bounds__(256) void nodepre_kernel(
        const float* __restrict__ ent, const float* __restrict__ nontext,
        const float* __restrict__ topic, const float* __restrict__ f1,
        const float* __restrict__ f2, const float* __restrict__ r1,
        const float* __restrict__ r2, const float* __restrict__ W1,
        float* __restrict__ head_pre, float* __restrict__ tail_pre, int N, int NTEXT) {
    __shared__ float Xs[KTOT][XST];   // [k][node], padded
    int t = threadIdx.x;
    int n0 = blockIdx.x * BM;

    // stage A-tile transposed: k<128 from ent/nontext
    {
        int tj = t & 31;      // k base
        int tn = t >> 5;      // node sub 0..7
#pragma unroll
        for (int it = 0; it < 8; ++it) {
            int node = it * 8 + tn;
            int ng = n0 + node;
            const float* src = (ng < NTEXT) ? (ent + (size_t)ng * E) : nontext;
            bool ok = ng < N;
#pragma unroll
            for (int m = 0; m < 4; ++m) {
                int k = tj + 32 * m;
                Xs[k][node] = ok ? src[k] : 0.f;
            }
        }
        if (t < BM) {
            int ng = n0 + t;
            bool ok = ng < N;
#pragma unroll
            for (int m = 0; m < 10; ++m) {
                const float* s = (m < 2) ? topic : (m < 4) ? f1 : (m < 6) ? f2 : (m < 8) ? r1 : r2;
                Xs[E + m][t] = ok ? s[(size_t)ng * 2 + (m & 1)] : 0.f;
            }
        }
    }
    __syncthreads();

    int tx = t & 31;   // col group: tx<16 head, else tail
    int ty = t >> 5;   // node group 0..7
    float acc[8][8];
#pragma unroll
    for (int i = 0; i < 8; ++i)
#pragma unroll
        for (int j = 0; j < 8; ++j) acc[i][j] = 0.f;

    const float* wbase = (tx < 16) ? (W1 + (size_t)OFF_HEAD * E + tx * 8)
                                   : (W1 + (size_t)OFF_TAIL * E + (tx - 16) * 8);
    for (int k = 0; k < KTOT; ++k) {
        float4 a0 = *(const float4*)&Xs[k][ty * 8];
        float4 a1 = *(const float4*)&Xs[k][ty * 8 + 4];
        const float* wr = wbase + (size_t)k * E;
        float4 w0 = *(const float4*)wr;
        float4 w1 = *(const float4*)(wr + 4);
        float av[8] = {a0.x, a0.y, a0.z, a0.w, a1.x, a1.y, a1.z, a1.w};
        float wv[8] = {w0.x, w0.y, w0.z, w0.w, w1.x, w1.y, w1.z, w1.w};
#pragma unroll
        for (int i = 0; i < 8; ++i)
#pragma unroll
            for (int j = 0; j < 8; ++j) acc[i][j] = fmaf(av[i], wv[j], acc[i][j]);
    }

    float* dst = (tx < 16) ? head_pre : tail_pre;
    int cx = (tx & 15) * 8;
#pragma unroll
    for (int i = 0; i < 8; ++i) {
        int node = n0 + ty * 8 + i;
        if (node < N) {
            float* d = dst + (size_t)node * E + cx;
            *(float4*)d = make_float4(acc[i][0], acc[i][1], acc[i][2], acc[i][3]);
            *(float4*)(d + 4) = make_float4(acc[i][4], acc[i][5], acc[i][6], acc[i][7]);
        }
    }
}

// 16 lanes per edge, 4 edges per wave
__global__ __launch_bounds__(256) void edge_kernel(
        const int* __restrict__ h_id, const int* __restrict__ r_id, const int* __restrict__ t_id,
        const float* __restrict__ head_pre, const float* __restrict__ rel_pre,
        const float* __restrict__ tail_pre, const float* __restrict__ bias3,
        const float* __restrict__ W2, const float* __restrict__ b2,
        float* __restrict__ out, int T) {
    int lane = threadIdx.x & 63;
    int sub = lane >> 4;        // edge within wave
    int sl = lane & 15;         // 16-lane slot: owns cols sl*8..sl*8+7
    int wid = blockIdx.x * (blockDim.x >> 6) + (threadIdx.x >> 6);
    int nw = gridDim.x * (blockDim.x >> 6);
    int c0 = sl * 8;

    float4 bi0a = *(const float4*)&bias3[c0],         bi0b = *(const float4*)&bias3[c0 + 4];
    float4 bi1a = *(const float4*)&bias3[E + c0],     bi1b = *(const float4*)&bias3[E + c0 + 4];
    float4 bi2a = *(const float4*)&bias3[2 * E + c0], bi2b = *(const float4*)&bias3[2 * E + c0 + 4];
    float4 w2a = *(const float4*)&W2[c0], w2b = *(const float4*)&W2[c0 + 4];
    float b2s = b2[0];

    int ne4 = (T + 3) >> 2;
    for (int e4 = wid; e4 < ne4; e4 += nw) {
        int e = e4 * 4 + sub;
        float p0 = 0.f, p1 = 0.f, p2 = 0.f;
        if (e < T) {
            int h = h_id[e], r = r_id[e], tt = t_id[e];
            const float4* hp = (const float4*)(head_pre + (size_t)h * E) + sl * 2;
            const float4* rp = (const float4*)(rel_pre + (size_t)r * E) + sl * 2;
            const float4* tp = (const float4*)(tail_pre + (size_t)tt * E) + sl * 2;
            float4 ha = hp[0], hb = hp[1];
            float4 ra = rp[0], rb = rp[1];
            float4 ta = tp[0], tb = tp[1];
            float s[8];
            s[0] = ha.x + ra.x + ta.x; s[1] = ha.y + ra.y + ta.y;
            s[2] = ha.z + ra.z + ta.z; s[3] = ha.w + ra.w + ta.w;
            s[4] = hb.x + rb.x + tb.x; s[5] = hb.y + rb.y + tb.y;
            s[6] = hb.z + rb.z + tb.z; s[7] = hb.w + rb.w + tb.w;
            float bi0[8] = {bi0a.x, bi0a.y, bi0a.z, bi0a.w, bi0b.x, bi0b.y, bi0b.z, bi0b.w};
            float bi1[8] = {bi1a.x, bi1a.y, bi1a.z, bi1a.w, bi1b.x, bi1b.y, bi1b.z, bi1b.w};
            float bi2[8] = {bi2a.x, bi2a.y, bi2a.z, bi2a.w, bi2b.x, bi2b.y, bi2b.z, bi2b.w};
            float w2v[8] = {w2a.x, w2a.y, w2a.z, w2a.w, w2b.x, w2b.y, w2b.z, w2b.w};
#pragma unroll
            for (int j = 0; j < 8; ++j) {
                p0 = fmaf(fmaxf(s[j] + bi0[j], 0.f), w2v[j], p0);
                p1 = fmaf(fmaxf(s[j] + bi1[j], 0.f), w2v[j], p1);
                p2 = fmaf(fmaxf(s[j] + bi2[j], 0.f), w2v[j], p2);
            }
        }
#pragma unroll
        for (int o = 1; o < 16; o <<= 1) {
            p0 += __shfl_xor(p0, o, 64);
            p1 += __shfl_xor(p1, o, 64);
            p2 += __shfl_xor(p2, o, 64);
        }
        if (e < T && sl < 3) {
            float v = (sl == 0) ? p0 : ((sl == 1) ? p1 : p2);
            out[(size_t)e * 3 + sl] = v + b2s;
        }
    }
}

extern "C" void kernel_launch(void* const* d_in, const int* in_sizes, int n_in,
                              void* d_out, int out_size, void* d_ws, size_t ws_size,
                              hipStream_t stream) {
    const int* h_id = (const int*)d_in[0];
    const int* r_id = (const int*)d_in[1];
    const int* t_id = (const int*)d_in[2];
    const float* q = (const float*)d_in[3];
    const float* ent = (const float*)d_in[4];
    const float* rel = (const float*)d_in[6];
    const float* topic = (const float*)d_in[7];
    const float* nontext = (const float*)d_in[8];
    const float* intent = (const float*)d_in[9];
    const float* W1 = (const float*)d_in[10];
    const float* b1 = (const float*)d_in[11];
    const float* W2 = (const float*)d_in[12];
    const float* b2 = (const float*)d_in[13];

    int T = in_sizes[0];
    int NTEXT = in_sizes[4] / E;
    int N = in_sizes[7] / 2;
    int NREL = in_sizes[6] / E;

    float* ws = (float*)d_ws;
    unsigned* cnt_fwd = (unsigned*)ws;              // N
    unsigned* cnt_rev = cnt_fwd + N;                // N
    float* pef1 = ws + 2 * (size_t)N;               // 2N
    float* per1 = ws + 4 * (size_t)N;               // 2N
    float* pef2 = ws + 6 * (size_t)N;               // 2N
    float* per2 = ws + 8 * (size_t)N;               // 2N
    float* bias3 = ws + 10 * (size_t)N;             // 3*E = 384
    float* rel_pre = bias3 + 3 * E;                 // NREL*E
    float* head_pre = rel_pre + (size_t)NREL * E;   // N*E
    float* tail_pre = head_pre + (size_t)N * E;     // N*E

    hipMemsetAsync(ws, 0, sizeof(float) * 10 * (size_t)N, stream);

    const int tb = 256;
    int gT = (T + tb - 1) / tb;
    int gN = (N + tb - 1) / tb;

    cs1_kernel<<<gT, tb, 0, stream>>>(h_id, t_id, topic, cnt_fwd, cnt_rev, pef1, per1, T);
    scale_kernel<<<gN, tb, 0, stream>>>(cnt_fwd, cnt_rev, pef1, per1, N);
    sc2_kernel<<<gT, tb, 0, stream>>>(h_id, t_id, pef1, per1, pef2, per2, T);
    scale_kernel<<<gN, tb, 0, stream>>>(cnt_fwd, cnt_rev, pef2, per2, N);

    bias_kernel<<<3, E, 0, stream>>>(intent, q, W1, b1, bias3);
    relpre_kernel<<<(NREL * E + tb - 1) / tb, tb, 0, stream>>>(rel, W1, rel_pre, NREL);
    nodepre_kernel<<<(N + BM - 1) / BM, tb, 0, stream>>>(ent, nontext, topic, pef1, pef2,
                                                         per1, per2, W1, head_pre, tail_pre,
                                                         N, NTEXT);
    edge_kernel<<<2048, tb, 0, stream>>>(h_id, r_id, t_id, head_pre, rel_pre, tail_pre,
                                         bias3, W2, b2, (float*)d_out, T);
}

// Round 3
// 232.574 us; speedup vs baseline: 1.7675x; 1.2611x over previous
//
#include <hip/hip_runtime.h>

#define E 128
#define OFF_Q 128
#define OFF_HEAD 256
#define OFF_REL 394
#define OFF_TAIL 522
#define KTOT 138      // 128 + 2 + 2*4
#define BM 64
#define XST 68        // padded LDS row stride (words)
#define RNG 2560      // nodes per LDS range
#define ECN 16        // edge chunks

// ---- round-1 scatter: per-(range,chunk) LDS binning, no global atomics ----
// bins: fwd {x,y,cnt} keyed by t, rev {x,y,cnt} keyed by h
__global__ __launch_bounds__(256) void scat1_kernel(
        const int* __restrict__ h_id, const int* __restrict__ t_id,
        const float* __restrict__ topic, float* __restrict__ part,
        int T, int N, int chunk) {
    __shared__ float bins[6][RNG];
    int tid = threadIdx.x;
    int n0 = blockIdx.x * RNG;
    int rlen = min(RNG, N - n0);
    int ec = blockIdx.y;
    for (int i = tid; i < 6 * RNG; i += 256) ((float*)bins)[i] = 0.f;
    __syncthreads();
    int e0 = ec * chunk;
    int e1 = min(T, e0 + chunk);
    for (int e = e0 + tid * 4; e < e1; e += 256 * 4) {
        int hh[4], tt[4];
        if (e + 3 < e1) {
            int4 h4 = *(const int4*)&h_id[e];
            int4 t4 = *(const int4*)&t_id[e];
            hh[0] = h4.x; hh[1] = h4.y; hh[2] = h4.z; hh[3] = h4.w;
            tt[0] = t4.x; tt[1] = t4.y; tt[2] = t4.z; tt[3] = t4.w;
        } else {
#pragma unroll
            for (int j = 0; j < 4; ++j) {
                hh[j] = (e + j < e1) ? h_id[e + j] : 0;
                tt[j] = (e + j < e1) ? t_id[e + j] : 0;
            }
        }
#pragma unroll
        for (int j = 0; j < 4; ++j) {
            if (e + j >= e1) break;
            int h = hh[j], t = tt[j];
            int rt = t - n0;
            if ((unsigned)rt < (unsigned)rlen) {
                float2 v = *(const float2*)&topic[2 * (size_t)h];
                atomicAdd(&bins[0][rt], v.x);
                atomicAdd(&bins[1][rt], v.y);
                atomicAdd(&bins[2][rt], 1.0f);
            }
            int rh = h - n0;
            if ((unsigned)rh < (unsigned)rlen) {
                float2 v = *(const float2*)&topic[2 * (size_t)t];
                atomicAdd(&bins[3][rh], v.x);
                atomicAdd(&bins[4][rh], v.y);
                atomicAdd(&bins[5][rh], 1.0f);
            }
        }
    }
    __syncthreads();
#pragma unroll
    for (int c = 0; c < 6; ++c)
        for (int r = tid; r < rlen; r += 256)
            part[((size_t)ec * 6 + c) * N + n0 + r] = bins[c][r];
}

__global__ __launch_bounds__(256) void reduce1_kernel(
        const float* __restrict__ part,
        float* __restrict__ pef1, float* __restrict__ per1,
        float* __restrict__ inv_fwd, float* __restrict__ inv_rev, int N) {
    int n = blockIdx.x * blockDim.x + threadIdx.x;
    if (n >= N) return;
    float s[6] = {0.f, 0.f, 0.f, 0.f, 0.f, 0.f};
#pragma unroll
    for (int ec = 0; ec < ECN; ++ec)
#pragma unroll
        for (int c = 0; c < 6; ++c)
            s[c] += part[((size_t)ec * 6 + c) * N + n];
    float invf = 1.0f / fmaxf(s[2], 1.0f);
    float invr = 1.0f / fmaxf(s[5], 1.0f);
    pef1[2 * n] = s[0] * invf;
    pef1[2 * n + 1] = s[1] * invf;
    per1[2 * n] = s[3] * invr;
    per1[2 * n + 1] = s[4] * invr;
    inv_fwd[n] = invf;
    inv_rev[n] = invr;
}

// ---- round-2 scatter: gathers scaled round-1 values ----
__global__ __launch_bounds__(256) void scat2_kernel(
        const int* __restrict__ h_id, const int* __restrict__ t_id,
        const float* __restrict__ pef1, const float* __restrict__ per1,
        float* __restrict__ part, int T, int N, int chunk) {
    __shared__ float bins[4][RNG];
    int tid = threadIdx.x;
    int n0 = blockIdx.x * RNG;
    int rlen = min(RNG, N - n0);
    int ec = blockIdx.y;
    for (int i = tid; i < 4 * RNG; i += 256) ((float*)bins)[i] = 0.f;
    __syncthreads();
    int e0 = ec * chunk;
    int e1 = min(T, e0 + chunk);
    for (int e = e0 + tid * 4; e < e1; e += 256 * 4) {
        int hh[4], tt[4];
        if (e + 3 < e1) {
            int4 h4 = *(const int4*)&h_id[e];
            int4 t4 = *(const int4*)&t_id[e];
            hh[0] = h4.x; hh[1] = h4.y; hh[2] = h4.z; hh[3] = h4.w;
            tt[0] = t4.x; tt[1] = t4.y; tt[2] = t4.z; tt[3] = t4.w;
        } else {
#pragma unroll
            for (int j = 0; j < 4; ++j) {
                hh[j] = (e + j < e1) ? h_id[e + j] : 0;
                tt[j] = (e + j < e1) ? t_id[e + j] : 0;
            }
        }
#pragma unroll
        for (int j = 0; j < 4; ++j) {
            if (e + j >= e1) break;
            int h = hh[j], t = tt[j];
            int rt = t - n0;
            if ((unsigned)rt < (unsigned)rlen) {
                float2 v = *(const float2*)&pef1[2 * (size_t)h];
                atomicAdd(&bins[0][rt], v.x);
                atomicAdd(&bins[1][rt], v.y);
            }
            int rh = h - n0;
            if ((unsigned)rh < (unsigned)rlen) {
                float2 v = *(const float2*)&per1[2 * (size_t)t];
                atomicAdd(&bins[2][rh], v.x);
                atomicAdd(&bins[3][rh], v.y);
            }
        }
    }
    __syncthreads();
#pragma unroll
    for (int c = 0; c < 4; ++c)
        for (int r = tid; r < rlen; r += 256)
            part[((size_t)ec * 4 + c) * N + n0 + r] = bins[c][r];
}

__global__ __launch_bounds__(256) void reduce2_kernel(
        const float* __restrict__ part,
        const float* __restrict__ inv_fwd, const float* __restrict__ inv_rev,
        float* __restrict__ pef2, float* __restrict__ per2, int N) {
    int n = blockIdx.x * blockDim.x + threadIdx.x;
    if (n >= N) return;
    float s[4] = {0.f, 0.f, 0.f, 0.f};
#pragma unroll
    for (int ec = 0; ec < ECN; ++ec)
#pragma unroll
        for (int c = 0; c < 4; ++c)
            s[c] += part[((size_t)ec * 4 + c) * N + n];
    float invf = inv_fwd[n], invr = inv_rev[n];
    pef2[2 * n] = s[0] * invf;
    pef2[2 * n + 1] = s[1] * invf;
    per2[2 * n] = s[2] * invr;
    per2[2 * n + 1] = s[3] * invr;
}

// bias3[i][j] = b1[j] + intent[i]·W1[0:128][j] + q·W1[128:256][j]
__global__ void bias_kernel(const float* __restrict__ intent, const float* __restrict__ q,
                            const float* __restrict__ W1, const float* __restrict__ b1,
                            float* __restrict__ bias3) {
    int i = blockIdx.x;
    int j = threadIdx.x;
    float acc = b1[j];
#pragma unroll 4
    for (int k = 0; k < E; ++k) acc += intent[i * E + k] * W1[k * E + j];
#pragma unroll 4
    for (int k = 0; k < E; ++k) acc += q[k] * W1[(OFF_Q + k) * E + j];
    bias3[i * E + j] = acc;
}

// rel_pre[r][j] = rel[r]·W1[OFF_REL:OFF_REL+128][j]
__global__ __launch_bounds__(256) void relpre_kernel(
        const float* __restrict__ rel, const float* __restrict__ W1,
        float* __restrict__ rel_pre, int NREL) {
    int idx = blockIdx.x * blockDim.x + threadIdx.x;
    int r = idx >> 7, j = idx & 127;
    if (r >= NREL) return;
    const float4* xr = (const float4*)(rel + (size_t)r * E);
    float acc = 0.f;
#pragma unroll
    for (int k4 = 0; k4 < 32; ++k4) {
        float4 x = xr[k4];
        int k = OFF_REL + k4 * 4;
        acc = fmaf(x.x, W1[(k + 0) * E + j], acc);
        acc = fmaf(x.y, W1[(k + 1) * E + j], acc);
        acc = fmaf(x.z, W1[(k + 2) * E + j], acc);
        acc = fmaf(x.w, W1[(k + 3) * E + j], acc);
    }
    rel_pre[idx] = acc;
}

// head_pre / tail_pre: register-tiled GEMM  [N x 138] @ [138 x 256]
__global__ __launch_bounds__(256) void nodepre_kernel(
        const float* __restrict__ ent, const float* __restrict__ nontext,
        const float* __restrict__ topic, const float* __restrict__ f1,
        const float* __restrict__ f2, const float* __restrict__ r1,
        const float* __restrict__ r2, const float* __restrict__ W1,
        float* __restrict__ head_pre, float* __restrict__ tail_pre, int N, int NTEXT) {
    __shared__ float Xs[KTOT][XST];   // [k][node], padded
    int t = threadIdx.x;
    int n0 = blockIdx.x * BM;
    {
        int tj = t & 31;
        int tn = t >> 5;
#pragma unroll
        for (int it = 0; it < 8; ++it) {
            int node = it * 8 + tn;
            int ng = n0 + node;
            const float* src = (ng < NTEXT) ? (ent + (size_t)ng * E) : nontext;
            bool ok = ng < N;
#pragma unroll
            for (int m = 0; m < 4; ++m) {
                int k = tj + 32 * m;
                Xs[k][node] = ok ? src[k] : 0.f;
            }
        }
        if (t < BM) {
            int ng = n0 + t;
            bool ok = ng < N;
#pragma unroll
            for (int m = 0; m < 10; ++m) {
                const float* s = (m < 2) ? topic : (m < 4) ? f1 : (m < 6) ? f2 : (m < 8) ? r1 : r2;
                Xs[E + m][t] = ok ? s[(size_t)ng * 2 + (m & 1)] : 0.f;
            }
        }
    }
    __syncthreads();

    int tx = t & 31;
    int ty = t >> 5;
    float acc[8][8];
#pragma unroll
    for (int i = 0; i < 8; ++i)
#pragma unroll
        for (int j = 0; j < 8; ++j) acc[i][j] = 0.f;

    const float* wbase = (tx < 16) ? (W1 + (size_t)OFF_HEAD * E + tx * 8)
                                   : (W1 + (size_t)OFF_TAIL * E + (tx - 16) * 8);
    for (int k = 0; k < KTOT; ++k) {
        float4 a0 = *(const float4*)&Xs[k][ty * 8];
        float4 a1 = *(const float4*)&Xs[k][ty * 8 + 4];
        const float* wr = wbase + (size_t)k * E;
        float4 w0 = *(const float4*)wr;
        float4 w1 = *(const float4*)(wr + 4);
        float av[8] = {a0.x, a0.y, a0.z, a0.w, a1.x, a1.y, a1.z, a1.w};
        float wv[8] = {w0.x, w0.y, w0.z, w0.w, w1.x, w1.y, w1.z, w1.w};
#pragma unroll
        for (int i = 0; i < 8; ++i)
#pragma unroll
            for (int j = 0; j < 8; ++j) acc[i][j] = fmaf(av[i], wv[j], acc[i][j]);
    }

    float* dst = (tx < 16) ? head_pre : tail_pre;
    int cx = (tx & 15) * 8;
#pragma unroll
    for (int i = 0; i < 8; ++i) {
        int node = n0 + ty * 8 + i;
        if (node < N) {
            float* d = dst + (size_t)node * E + cx;
            *(float4*)d = make_float4(acc[i][0], acc[i][1], acc[i][2], acc[i][3]);
            *(float4*)(d + 4) = make_float4(acc[i][4], acc[i][5], acc[i][6], acc[i][7]);
        }
    }
}

// 16 lanes per edge, 4 edges per wave
__global__ __launch_bounds__(256) void edge_kernel(
        const int* __restrict__ h_id, const int* __restrict__ r_id, const int* __restrict__ t_id,
        const float* __restrict__ head_pre, const float* __restrict__ rel_pre,
        const float* __restrict__ tail_pre, const float* __restrict__ bias3,
        const float* __restrict__ W2, const float* __restrict__ b2,
        float* __restrict__ out, int T) {
    int lane = threadIdx.x & 63;
    int sub = lane >> 4;
    int sl = lane & 15;
    int wid = blockIdx.x * (blockDim.x >> 6) + (threadIdx.x >> 6);
    int nw = gridDim.x * (blockDim.x >> 6);
    int c0 = sl * 8;

    float4 bi0a = *(const float4*)&bias3[c0],         bi0b = *(const float4*)&bias3[c0 + 4];
    float4 bi1a = *(const float4*)&bias3[E + c0],     bi1b = *(const float4*)&bias3[E + c0 + 4];
    float4 bi2a = *(const float4*)&bias3[2 * E + c0], bi2b = *(const float4*)&bias3[2 * E + c0 + 4];
    float4 w2a = *(const float4*)&W2[c0], w2b = *(const float4*)&W2[c0 + 4];
    float b2s = b2[0];

    int ne4 = (T + 3) >> 2;
    for (int e4 = wid; e4 < ne4; e4 += nw) {
        int e = e4 * 4 + sub;
        float p0 = 0.f, p1 = 0.f, p2 = 0.f;
        if (e < T) {
            int h = h_id[e], r = r_id[e], tt = t_id[e];
            const float4* hp = (const float4*)(head_pre + (size_t)h * E) + sl * 2;
            const float4* rp = (const float4*)(rel_pre + (size_t)r * E) + sl * 2;
            const float4* tp = (const float4*)(tail_pre + (size_t)tt * E) + sl * 2;
            float4 ha = hp[0], hb = hp[1];
            float4 ra = rp[0], rb = rp[1];
            float4 ta = tp[0], tb = tp[1];
            float s[8];
            s[0] = ha.x + ra.x + ta.x; s[1] = ha.y + ra.y + ta.y;
            s[2] = ha.z + ra.z + ta.z; s[3] = ha.w + ra.w + ta.w;
            s[4] = hb.x + rb.x + tb.x; s[5] = hb.y + rb.y + tb.y;
            s[6] = hb.z + rb.z + tb.z; s[7] = hb.w + rb.w + tb.w;
            float bi0[8] = {bi0a.x, bi0a.y, bi0a.z, bi0a.w, bi0b.x, bi0b.y, bi0b.z, bi0b.w};
            float bi1[8] = {bi1a.x, bi1a.y, bi1a.z, bi1a.w, bi1b.x, bi1b.y, bi1b.z, bi1b.w};
            float bi2[8] = {bi2a.x, bi2a.y, bi2a.z, bi2a.w, bi2b.x, bi2b.y, bi2b.z, bi2b.w};
            float w2v[8] = {w2a.x, w2a.y, w2a.z, w2a.w, w2b.x, w2b.y, w2b.z, w2b.w};
#pragma unroll
            for (int j = 0; j < 8; ++j) {
                p0 = fmaf(fmaxf(s[j] + bi0[j], 0.f), w2v[j], p0);
                p1 = fmaf(fmaxf(s[j] + bi1[j], 0.f), w2v[j], p1);
                p2 = fmaf(fmaxf(s[j] + bi2[j], 0.f), w2v[j], p2);
            }
        }
#pragma unroll
        for (int o = 1; o < 16; o <<= 1) {
            p0 += __shfl_xor(p0, o, 64);
            p1 += __shfl_xor(p1, o, 64);
            p2 += __shfl_xor(p2, o, 64);
        }
        if (e < T && sl < 3) {
            float v = (sl == 0) ? p0 : ((sl == 1) ? p1 : p2);
            out[(size_t)e * 3 + sl] = v + b2s;
        }
    }
}

extern "C" void kernel_launch(void* const* d_in, const int* in_sizes, int n_in,
                              void* d_out, int out_size, void* d_ws, size_t ws_size,
                              hipStream_t stream) {
    const int* h_id = (const int*)d_in[0];
    const int* r_id = (const int*)d_in[1];
    const int* t_id = (const int*)d_in[2];
    const float* q = (const float*)d_in[3];
    const float* ent = (const float*)d_in[4];
    const float* rel = (const float*)d_in[6];
    const float* topic = (const float*)d_in[7];
    const float* nontext = (const float*)d_in[8];
    const float* intent = (const float*)d_in[9];
    const float* W1 = (const float*)d_in[10];
    const float* b1 = (const float*)d_in[11];
    const float* W2 = (const float*)d_in[12];
    const float* b2 = (const float*)d_in[13];

    int T = in_sizes[0];
    int NTEXT = in_sizes[4] / E;
    int N = in_sizes[7] / 2;
    int NREL = in_sizes[6] / E;

    float* ws = (float*)d_ws;
    float* inv_fwd = ws;                            // N
    float* inv_rev = ws + (size_t)N;                // N
    float* pef1 = ws + 2 * (size_t)N;               // 2N
    float* per1 = ws + 4 * (size_t)N;               // 2N
    float* pef2 = ws + 6 * (size_t)N;               // 2N
    float* per2 = ws + 8 * (size_t)N;               // 2N
    float* bias3 = ws + 10 * (size_t)N;             // 3*E
    float* rel_pre = bias3 + 3 * E;                 // NREL*E
    float* head_pre = rel_pre + (size_t)NREL * E;   // N*E
    float* tail_pre = head_pre + (size_t)N * E;     // N*E
    float* part = head_pre;  // alias: partials (ECN*6*N floats) live before nodepre runs

    const int tb = 256;
    int RC = (N + RNG - 1) / RNG;
    int chunk = ((T + ECN - 1) / ECN + 3) & ~3;
    dim3 sg(RC, ECN);

    scat1_kernel<<<sg, tb, 0, stream>>>(h_id, t_id, topic, part, T, N, chunk);
    reduce1_kernel<<<(N + tb - 1) / tb, tb, 0, stream>>>(part, pef1, per1, inv_fwd, inv_rev, N);
    scat2_kernel<<<sg, tb, 0, stream>>>(h_id, t_id, pef1, per1, part, T, N, chunk);
    reduce2_kernel<<<(N + tb - 1) / tb, tb, 0, stream>>>(part, inv_fwd, inv_rev, pef2, per2, N);

    bias_kernel<<<3, E, 0, stream>>>(intent, q, W1, b1, bias3);
    relpre_kernel<<<(NREL * E + tb - 1) / tb, tb, 0, stream>>>(rel, W1, rel_pre, NREL);
    nodepre_kernel<<<(N + BM - 1) / BM, tb, 0, stream>>>(ent, nontext, topic, pef1, pef2,
                                                         per1, per2, W1, head_pre, tail_pre,
                                                         N, NTEXT);
    edge_kernel<<<2048, tb, 0, stream>>>(h_id, r_id, t_id, head_pre, rel_pre, tail_pre,
                                         bias3, W2, b2, (float*)d_out, T);
}

// Round 4
// 210.013 us; speedup vs baseline: 1.9574x; 1.1074x over previous
//
#include <hip/hip_runtime.h>

#define E 128
#define OFF_Q 128
#define OFF_HEAD 256
#define OFF_REL 394
#define OFF_TAIL 522
#define KTOT 138      // 128 + 2 + 2*4
#define BM 64
#define XST 68        // padded LDS row stride (words)
#define RNG 2560      // nodes per LDS range
#define ECN 16        // edge chunks

// ---- bf16 helpers (hand-rolled RNE, finite values only) ----
__device__ __forceinline__ unsigned short f2bf(float f) {
    unsigned u = __float_as_uint(f);
    return (unsigned short)((u + 0x7fffu + ((u >> 16) & 1u)) >> 16);
}
__device__ __forceinline__ unsigned bpack(float lo, float hi) {
    return (unsigned)f2bf(lo) | ((unsigned)f2bf(hi) << 16);
}
__device__ __forceinline__ float blo(unsigned u) { return __uint_as_float(u << 16); }
__device__ __forceinline__ float bhi(unsigned u) { return __uint_as_float(u & 0xffff0000u); }

// ---- round-1 scatter: per-(range,chunk) LDS binning, no global atomics ----
__global__ __launch_bounds__(256) void scat1_kernel(
        const int* __restrict__ h_id, const int* __restrict__ t_id,
        const float* __restrict__ topic, float* __restrict__ part,
        int T, int N, int chunk) {
    __shared__ float bins[6][RNG];
    int tid = threadIdx.x;
    int n0 = blockIdx.x * RNG;
    int rlen = min(RNG, N - n0);
    int ec = blockIdx.y;
    for (int i = tid; i < 6 * RNG; i += 256) ((float*)bins)[i] = 0.f;
    __syncthreads();
    int e0 = ec * chunk;
    int e1 = min(T, e0 + chunk);
    for (int e = e0 + tid * 4; e < e1; e += 256 * 4) {
        int hh[4], tt[4];
        if (e + 3 < e1) {
            int4 h4 = *(const int4*)&h_id[e];
            int4 t4 = *(const int4*)&t_id[e];
            hh[0] = h4.x; hh[1] = h4.y; hh[2] = h4.z; hh[3] = h4.w;
            tt[0] = t4.x; tt[1] = t4.y; tt[2] = t4.z; tt[3] = t4.w;
        } else {
#pragma unroll
            for (int j = 0; j < 4; ++j) {
                hh[j] = (e + j < e1) ? h_id[e + j] : 0;
                tt[j] = (e + j < e1) ? t_id[e + j] : 0;
            }
        }
#pragma unroll
        for (int j = 0; j < 4; ++j) {
            if (e + j >= e1) break;
            int h = hh[j], t = tt[j];
            int rt = t - n0;
            if ((unsigned)rt < (unsigned)rlen) {
                float2 v = *(const float2*)&topic[2 * (size_t)h];
                atomicAdd(&bins[0][rt], v.x);
                atomicAdd(&bins[1][rt], v.y);
                atomicAdd(&bins[2][rt], 1.0f);
            }
            int rh = h - n0;
            if ((unsigned)rh < (unsigned)rlen) {
                float2 v = *(const float2*)&topic[2 * (size_t)t];
                atomicAdd(&bins[3][rh], v.x);
                atomicAdd(&bins[4][rh], v.y);
                atomicAdd(&bins[5][rh], 1.0f);
            }
        }
    }
    __syncthreads();
#pragma unroll
    for (int c = 0; c < 6; ++c)
        for (int r = tid; r < rlen; r += 256)
            part[((size_t)ec * 6 + c) * N + n0 + r] = bins[c][r];
}

__global__ __launch_bounds__(256) void reduce1_kernel(
        const float* __restrict__ part,
        float* __restrict__ pef1, float* __restrict__ per1,
        float* __restrict__ inv_fwd, float* __restrict__ inv_rev, int N) {
    int n = blockIdx.x * blockDim.x + threadIdx.x;
    if (n >= N) return;
    float s[6] = {0.f, 0.f, 0.f, 0.f, 0.f, 0.f};
#pragma unroll
    for (int ec = 0; ec < ECN; ++ec)
#pragma unroll
        for (int c = 0; c < 6; ++c)
            s[c] += part[((size_t)ec * 6 + c) * N + n];
    float invf = 1.0f / fmaxf(s[2], 1.0f);
    float invr = 1.0f / fmaxf(s[5], 1.0f);
    pef1[2 * n] = s[0] * invf;
    pef1[2 * n + 1] = s[1] * invf;
    per1[2 * n] = s[3] * invr;
    per1[2 * n + 1] = s[4] * invr;
    inv_fwd[n] = invf;
    inv_rev[n] = invr;
}

__global__ __launch_bounds__(256) void scat2_kernel(
        const int* __restrict__ h_id, const int* __restrict__ t_id,
        const float* __restrict__ pef1, const float* __restrict__ per1,
        float* __restrict__ part, int T, int N, int chunk) {
    __shared__ float bins[4][RNG];
    int tid = threadIdx.x;
    int n0 = blockIdx.x * RNG;
    int rlen = min(RNG, N - n0);
    int ec = blockIdx.y;
    for (int i = tid; i < 4 * RNG; i += 256) ((float*)bins)[i] = 0.f;
    __syncthreads();
    int e0 = ec * chunk;
    int e1 = min(T, e0 + chunk);
    for (int e = e0 + tid * 4; e < e1; e += 256 * 4) {
        int hh[4], tt[4];
        if (e + 3 < e1) {
            int4 h4 = *(const int4*)&h_id[e];
            int4 t4 = *(const int4*)&t_id[e];
            hh[0] = h4.x; hh[1] = h4.y; hh[2] = h4.z; hh[3] = h4.w;
            tt[0] = t4.x; tt[1] = t4.y; tt[2] = t4.z; tt[3] = t4.w;
        } else {
#pragma unroll
            for (int j = 0; j < 4; ++j) {
                hh[j] = (e + j < e1) ? h_id[e + j] : 0;
                tt[j] = (e + j < e1) ? t_id[e + j] : 0;
            }
        }
#pragma unroll
        for (int j = 0; j < 4; ++j) {
            if (e + j >= e1) break;
            int h = hh[j], t = tt[j];
            int rt = t - n0;
            if ((unsigned)rt < (unsigned)rlen) {
                float2 v = *(const float2*)&pef1[2 * (size_t)h];
                atomicAdd(&bins[0][rt], v.x);
                atomicAdd(&bins[1][rt], v.y);
            }
            int rh = h - n0;
            if ((unsigned)rh < (unsigned)rlen) {
                float2 v = *(const float2*)&per1[2 * (size_t)t];
                atomicAdd(&bins[2][rh], v.x);
                atomicAdd(&bins[3][rh], v.y);
            }
        }
    }
    __syncthreads();
#pragma unroll
    for (int c = 0; c < 4; ++c)
        for (int r = tid; r < rlen; r += 256)
            part[((size_t)ec * 4 + c) * N + n0 + r] = bins[c][r];
}

__global__ __launch_bounds__(256) void reduce2_kernel(
        const float* __restrict__ part,
        const float* __restrict__ inv_fwd, const float* __restrict__ inv_rev,
        float* __restrict__ pef2, float* __restrict__ per2, int N) {
    int n = blockIdx.x * blockDim.x + threadIdx.x;
    if (n >= N) return;
    float s[4] = {0.f, 0.f, 0.f, 0.f};
#pragma unroll
    for (int ec = 0; ec < ECN; ++ec)
#pragma unroll
        for (int c = 0; c < 4; ++c)
            s[c] += part[((size_t)ec * 4 + c) * N + n];
    float invf = inv_fwd[n], invr = inv_rev[n];
    pef2[2 * n] = s[0] * invf;
    pef2[2 * n + 1] = s[1] * invf;
    per2[2 * n] = s[2] * invr;
    per2[2 * n + 1] = s[3] * invr;
}

// bias3[i][j] = b1[j] + intent[i]·W1[0:128][j] + q·W1[128:256][j]  (fp32)
__global__ void bias_kernel(const float* __restrict__ intent, const float* __restrict__ q,
                            const float* __restrict__ W1, const float* __restrict__ b1,
                            float* __restrict__ bias3) {
    int i = blockIdx.x;
    int j = threadIdx.x;
    float acc = b1[j];
#pragma unroll 4
    for (int k = 0; k < E; ++k) acc += intent[i * E + k] * W1[k * E + j];
#pragma unroll 4
    for (int k = 0; k < E; ++k) acc += q[k] * W1[(OFF_Q + k) * E + j];
    bias3[i * E + j] = acc;
}

// rel_pre (bf16)
__global__ __launch_bounds__(256) void relpre_kernel(
        const float* __restrict__ rel, const float* __restrict__ W1,
        unsigned short* __restrict__ rel_bf, int NREL) {
    int idx = blockIdx.x * blockDim.x + threadIdx.x;
    int r = idx >> 7, j = idx & 127;
    if (r >= NREL) return;
    const float4* xr = (const float4*)(rel + (size_t)r * E);
    float acc = 0.f;
#pragma unroll
    for (int k4 = 0; k4 < 32; ++k4) {
        float4 x = xr[k4];
        int k = OFF_REL + k4 * 4;
        acc = fmaf(x.x, W1[(k + 0) * E + j], acc);
        acc = fmaf(x.y, W1[(k + 1) * E + j], acc);
        acc = fmaf(x.z, W1[(k + 2) * E + j], acc);
        acc = fmaf(x.w, W1[(k + 3) * E + j], acc);
    }
    rel_bf[idx] = f2bf(acc);
}

// head/tail precompute: register-tiled GEMM [Nx138]@[138x256], bf16 out,
// software-pipelined (prefetch k+1 Xs frags + W1 rows into registers)
__global__ __launch_bounds__(256) void nodepre_kernel(
        const float* __restrict__ ent, const float* __restrict__ nontext,
        const float* __restrict__ topic, const float* __restrict__ f1,
        const float* __restrict__ f2, const float* __restrict__ r1,
        const float* __restrict__ r2, const float* __restrict__ W1,
        unsigned short* __restrict__ head_bf, unsigned short* __restrict__ tail_bf,
        int N, int NTEXT) {
    __shared__ float Xs[KTOT][XST];   // [k][node], padded
    int t = threadIdx.x;
    int n0 = blockIdx.x * BM;
    {
        int tj = t & 31;
        int tn = t >> 5;
#pragma unroll
        for (int it = 0; it < 8; ++it) {
            int node = it * 8 + tn;
            int ng = n0 + node;
            const float* src = (ng < NTEXT) ? (ent + (size_t)ng * E) : nontext;
            bool ok = ng < N;
#pragma unroll
            for (int m = 0; m < 4; ++m) {
                int k = tj + 32 * m;
                Xs[k][node] = ok ? src[k] : 0.f;
            }
        }
        if (t < BM) {
            int ng = n0 + t;
            bool ok = ng < N;
#pragma unroll
            for (int m = 0; m < 10; ++m) {
                const float* s = (m < 2) ? topic : (m < 4) ? f1 : (m < 6) ? f2 : (m < 8) ? r1 : r2;
                Xs[E + m][t] = ok ? s[(size_t)ng * 2 + (m & 1)] : 0.f;
            }
        }
    }
    __syncthreads();

    int tx = t & 31;
    int ty = t >> 5;
    float acc[8][8];
#pragma unroll
    for (int i = 0; i < 8; ++i)
#pragma unroll
        for (int j = 0; j < 8; ++j) acc[i][j] = 0.f;

    const float* wbase = (tx < 16) ? (W1 + (size_t)OFF_HEAD * E + tx * 8)
                                   : (W1 + (size_t)OFF_TAIL * E + (tx - 16) * 8);
    float4 a0 = *(const float4*)&Xs[0][ty * 8];
    float4 a1 = *(const float4*)&Xs[0][ty * 8 + 4];
    float4 w0 = *(const float4*)wbase;
    float4 w1 = *(const float4*)(wbase + 4);
#pragma unroll 2
    for (int k = 0; k < KTOT; ++k) {
        int kn = (k < KTOT - 1) ? k + 1 : k;
        float4 na0 = *(const float4*)&Xs[kn][ty * 8];
        float4 na1 = *(const float4*)&Xs[kn][ty * 8 + 4];
        const float* wrn = wbase + (size_t)kn * E;
        float4 nw0 = *(const float4*)wrn;
        float4 nw1 = *(const float4*)(wrn + 4);
        float av[8] = {a0.x, a0.y, a0.z, a0.w, a1.x, a1.y, a1.z, a1.w};
        float wv[8] = {w0.x, w0.y, w0.z, w0.w, w1.x, w1.y, w1.z, w1.w};
#pragma unroll
        for (int i = 0; i < 8; ++i)
#pragma unroll
            for (int j = 0; j < 8; ++j) acc[i][j] = fmaf(av[i], wv[j], acc[i][j]);
        a0 = na0; a1 = na1; w0 = nw0; w1 = nw1;
    }

    unsigned short* dst = (tx < 16) ? head_bf : tail_bf;
    int cx = (tx & 15) * 8;
#pragma unroll
    for (int i = 0; i < 8; ++i) {
        int node = n0 + ty * 8 + i;
        if (node < N) {
            uint4 v;
            v.x = bpack(acc[i][0], acc[i][1]);
            v.y = bpack(acc[i][2], acc[i][3]);
            v.z = bpack(acc[i][4], acc[i][5]);
            v.w = bpack(acc[i][6], acc[i][7]);
            *(uint4*)(dst + (size_t)node * E + cx) = v;
        }
    }
}

// 16 lanes per edge, 4 edges per wave; bf16 table gathers
__global__ __launch_bounds__(256) void edge_kernel(
        const int* __restrict__ h_id, const int* __restrict__ r_id, const int* __restrict__ t_id,
        const unsigned short* __restrict__ head_bf, const unsigned short* __restrict__ rel_bf,
        const unsigned short* __restrict__ tail_bf, const float* __restrict__ bias3,
        const float* __restrict__ W2, const float* __restrict__ b2,
        float* __restrict__ out, int T) {
    int lane = threadIdx.x & 63;
    int sub = lane >> 4;
    int sl = lane & 15;
    int wid = blockIdx.x * (blockDim.x >> 6) + (threadIdx.x >> 6);
    int nw = gridDim.x * (blockDim.x >> 6);
    int c0 = sl * 8;

    float4 bi0a = *(const float4*)&bias3[c0],         bi0b = *(const float4*)&bias3[c0 + 4];
    float4 bi1a = *(const float4*)&bias3[E + c0],     bi1b = *(const float4*)&bias3[E + c0 + 4];
    float4 bi2a = *(const float4*)&bias3[2 * E + c0], bi2b = *(const float4*)&bias3[2 * E + c0 + 4];
    float4 w2a = *(const float4*)&W2[c0], w2b = *(const float4*)&W2[c0 + 4];
    float b2s = b2[0];

    int ne4 = (T + 3) >> 2;
    for (int e4 = wid; e4 < ne4; e4 += nw) {
        int e = e4 * 4 + sub;
        float p0 = 0.f, p1 = 0.f, p2 = 0.f;
        if (e < T) {
            int h = h_id[e], r = r_id[e], tt = t_id[e];
            uint4 hu = *(const uint4*)(head_bf + (size_t)h * E + c0);
            uint4 ru = *(const uint4*)(rel_bf + (size_t)r * E + c0);
            uint4 tu = *(const uint4*)(tail_bf + (size_t)tt * E + c0);
            float s[8];
            s[0] = blo(hu.x) + blo(ru.x) + blo(tu.x);
            s[1] = bhi(hu.x) + bhi(ru.x) + bhi(tu.x);
            s[2] = blo(hu.y) + blo(ru.y) + blo(tu.y);
            s[3] = bhi(hu.y) + bhi(ru.y) + bhi(tu.y);
            s[4] = blo(hu.z) + blo(ru.z) + blo(tu.z);
            s[5] = bhi(hu.z) + bhi(ru.z) + bhi(tu.z);
            s[6] = blo(hu.w) + blo(ru.w) + blo(tu.w);
            s[7] = bhi(hu.w) + bhi(ru.w) + bhi(tu.w);
            float bi0[8] = {bi0a.x, bi0a.y, bi0a.z, bi0a.w, bi0b.x, bi0b.y, bi0b.z, bi0b.w};
            float bi1[8] = {bi1a.x, bi1a.y, bi1a.z, bi1a.w, bi1b.x, bi1b.y, bi1b.z, bi1b.w};
            float bi2[8] = {bi2a.x, bi2a.y, bi2a.z, bi2a.w, bi2b.x, bi2b.y, bi2b.z, bi2b.w};
            float w2v[8] = {w2a.x, w2a.y, w2a.z, w2a.w, w2b.x, w2b.y, w2b.z, w2b.w};
#pragma unroll
            for (int j = 0; j < 8; ++j) {
                p0 = fmaf(fmaxf(s[j] + bi0[j], 0.f), w2v[j], p0);
                p1 = fmaf(fmaxf(s[j] + bi1[j], 0.f), w2v[j], p1);
                p2 = fmaf(fmaxf(s[j] + bi2[j], 0.f), w2v[j], p2);
            }
        }
#pragma unroll
        for (int o = 1; o < 16; o <<= 1) {
            p0 += __shfl_xor(p0, o, 64);
            p1 += __shfl_xor(p1, o, 64);
            p2 += __shfl_xor(p2, o, 64);
        }
        if (e < T && sl < 3) {
            float v = (sl == 0) ? p0 : ((sl == 1) ? p1 : p2);
            out[(size_t)e * 3 + sl] = v + b2s;
        }
    }
}

extern "C" void kernel_launch(void* const* d_in, const int* in_sizes, int n_in,
                              void* d_out, int out_size, void* d_ws, size_t ws_size,
                              hipStream_t stream) {
    const int* h_id = (const int*)d_in[0];
    const int* r_id = (const int*)d_in[1];
    const int* t_id = (const int*)d_in[2];
    const float* q = (const float*)d_in[3];
    const float* ent = (const float*)d_in[4];
    const float* rel = (const float*)d_in[6];
    const float* topic = (const float*)d_in[7];
    const float* nontext = (const float*)d_in[8];
    const float* intent = (const float*)d_in[9];
    const float* W1 = (const float*)d_in[10];
    const float* b1 = (const float*)d_in[11];
    const float* W2 = (const float*)d_in[12];
    const float* b2 = (const float*)d_in[13];

    int T = in_sizes[0];
    int NTEXT = in_sizes[4] / E;
    int N = in_sizes[7] / 2;
    int NREL = in_sizes[6] / E;

    float* ws = (float*)d_ws;
    float* inv_fwd = ws;                            // N
    float* inv_rev = ws + (size_t)N;                // N
    float* pef1 = ws + 2 * (size_t)N;               // 2N
    float* per1 = ws + 4 * (size_t)N;               // 2N
    float* pef2 = ws + 6 * (size_t)N;               // 2N
    float* per2 = ws + 8 * (size_t)N;               // 2N
    float* bias3 = ws + 10 * (size_t)N;             // 3*E = 384
    float* part = bias3 + 3 * E;                    // ECN*6*N floats
    float* after_part = part + (size_t)ECN * 6 * N;
    unsigned short* rel_bf = (unsigned short*)after_part;          // NREL*E bf16
    unsigned short* head_bf = rel_bf + (size_t)NREL * E;           // N*E bf16
    unsigned short* tail_bf = head_bf + (size_t)N * E;             // N*E bf16

    const int tb = 256;
    int RC = (N + RNG - 1) / RNG;
    int chunk = ((T + ECN - 1) / ECN + 3) & ~3;
    dim3 sg(RC, ECN);

    scat1_kernel<<<sg, tb, 0, stream>>>(h_id, t_id, topic, part, T, N, chunk);
    reduce1_kernel<<<(N + tb - 1) / tb, tb, 0, stream>>>(part, pef1, per1, inv_fwd, inv_rev, N);
    scat2_kernel<<<sg, tb, 0, stream>>>(h_id, t_id, pef1, per1, part, T, N, chunk);
    reduce2_kernel<<<(N + tb - 1) / tb, tb, 0, stream>>>(part, inv_fwd, inv_rev, pef2, per2, N);

    bias_kernel<<<3, E, 0, stream>>>(intent, q, W1, b1, bias3);
    relpre_kernel<<<(NREL * E + tb - 1) / tb, tb, 0, stream>>>(rel, W1, rel_bf, NREL);
    nodepre_kernel<<<(N + BM - 1) / BM, tb, 0, stream>>>(ent, nontext, topic, pef1, pef2,
                                                         per1, per2, W1, head_bf, tail_bf,
                                                         N, NTEXT);
    edge_kernel<<<2048, tb, 0, stream>>>(h_id, r_id, t_id, head_bf, rel_bf, tail_bf,
                                         bias3, W2, b2, (float*)d_out, T);
}

// Round 5
// 186.909 us; speedup vs baseline: 2.1993x; 1.1236x over previous
//
#include <hip/hip_runtime.h>

#define E 128
#define OFF_Q 128
#define OFF_HEAD 256
#define OFF_REL 394
#define OFF_TAIL 522
#define KTOT 138      // 128 + 2 + 2*4
#define KP 160        // K padded to 5*32
#define AST 168       // LDS A row stride in bf16 (84 words -> conflict-free-ish)
#define RNG 2560      // nodes per LDS range
#define ECN 16        // edge chunks

typedef __attribute__((ext_vector_type(8))) short short8;
typedef __attribute__((ext_vector_type(4))) float f32x4;

// ---- bf16 helpers (RNE, finite values only) ----
__device__ __forceinline__ unsigned short f2bf(float f) {
    unsigned u = __float_as_uint(f);
    return (unsigned short)((u + 0x7fffu + ((u >> 16) & 1u)) >> 16);
}
__device__ __forceinline__ unsigned bpack(float lo, float hi) {
    return (unsigned)f2bf(lo) | ((unsigned)f2bf(hi) << 16);
}
__device__ __forceinline__ float blo(unsigned u) { return __uint_as_float(u << 16); }
__device__ __forceinline__ float bhi(unsigned u) { return __uint_as_float(u & 0xffff0000u); }

// ---- round-1 scatter: per-(range,chunk) LDS binning, no global atomics ----
__global__ __launch_bounds__(256) void scat1_kernel(
        const int* __restrict__ h_id, const int* __restrict__ t_id,
        const float* __restrict__ topic, float* __restrict__ part,
        int T, int N, int chunk) {
    __shared__ float bins[6][RNG];
    int tid = threadIdx.x;
    int n0 = blockIdx.x * RNG;
    int rlen = min(RNG, N - n0);
    int ec = blockIdx.y;
    for (int i = tid; i < 6 * RNG; i += 256) ((float*)bins)[i] = 0.f;
    __syncthreads();
    int e0 = ec * chunk;
    int e1 = min(T, e0 + chunk);
    for (int e = e0 + tid * 4; e < e1; e += 256 * 4) {
        int hh[4], tt[4];
        if (e + 3 < e1) {
            int4 h4 = *(const int4*)&h_id[e];
            int4 t4 = *(const int4*)&t_id[e];
            hh[0] = h4.x; hh[1] = h4.y; hh[2] = h4.z; hh[3] = h4.w;
            tt[0] = t4.x; tt[1] = t4.y; tt[2] = t4.z; tt[3] = t4.w;
        } else {
#pragma unroll
            for (int j = 0; j < 4; ++j) {
                hh[j] = (e + j < e1) ? h_id[e + j] : 0;
                tt[j] = (e + j < e1) ? t_id[e + j] : 0;
            }
        }
#pragma unroll
        for (int j = 0; j < 4; ++j) {
            if (e + j >= e1) break;
            int h = hh[j], t = tt[j];
            int rt = t - n0;
            if ((unsigned)rt < (unsigned)rlen) {
                float2 v = *(const float2*)&topic[2 * (size_t)h];
                atomicAdd(&bins[0][rt], v.x);
                atomicAdd(&bins[1][rt], v.y);
                atomicAdd(&bins[2][rt], 1.0f);
            }
            int rh = h - n0;
            if ((unsigned)rh < (unsigned)rlen) {
                float2 v = *(const float2*)&topic[2 * (size_t)t];
                atomicAdd(&bins[3][rh], v.x);
                atomicAdd(&bins[4][rh], v.y);
                atomicAdd(&bins[5][rh], 1.0f);
            }
        }
    }
    __syncthreads();
#pragma unroll
    for (int c = 0; c < 6; ++c)
        for (int r = tid; r < rlen; r += 256)
            part[((size_t)ec * 6 + c) * N + n0 + r] = bins[c][r];
}

__global__ __launch_bounds__(256) void reduce1_kernel(
        const float* __restrict__ part,
        float* __restrict__ pef1, float* __restrict__ per1,
        float* __restrict__ inv_fwd, float* __restrict__ inv_rev, int N) {
    int n = blockIdx.x * blockDim.x + threadIdx.x;
    if (n >= N) return;
    float s[6] = {0.f, 0.f, 0.f, 0.f, 0.f, 0.f};
#pragma unroll
    for (int ec = 0; ec < ECN; ++ec)
#pragma unroll
        for (int c = 0; c < 6; ++c)
            s[c] += part[((size_t)ec * 6 + c) * N + n];
    float invf = 1.0f / fmaxf(s[2], 1.0f);
    float invr = 1.0f / fmaxf(s[5], 1.0f);
    pef1[2 * n] = s[0] * invf;
    pef1[2 * n + 1] = s[1] * invf;
    per1[2 * n] = s[3] * invr;
    per1[2 * n + 1] = s[4] * invr;
    inv_fwd[n] = invf;
    inv_rev[n] = invr;
}

__global__ __launch_bounds__(256) void scat2_kernel(
        const int* __restrict__ h_id, const int* __restrict__ t_id,
        const float* __restrict__ pef1, const float* __restrict__ per1,
        float* __restrict__ part, int T, int N, int chunk) {
    __shared__ float bins[4][RNG];
    int tid = threadIdx.x;
    int n0 = blockIdx.x * RNG;
    int rlen = min(RNG, N - n0);
    int ec = blockIdx.y;
    for (int i = tid; i < 4 * RNG; i += 256) ((float*)bins)[i] = 0.f;
    __syncthreads();
    int e0 = ec * chunk;
    int e1 = min(T, e0 + chunk);
    for (int e = e0 + tid * 4; e < e1; e += 256 * 4) {
        int hh[4], tt[4];
        if (e + 3 < e1) {
            int4 h4 = *(const int4*)&h_id[e];
            int4 t4 = *(const int4*)&t_id[e];
            hh[0] = h4.x; hh[1] = h4.y; hh[2] = h4.z; hh[3] = h4.w;
            tt[0] = t4.x; tt[1] = t4.y; tt[2] = t4.z; tt[3] = t4.w;
        } else {
#pragma unroll
            for (int j = 0; j < 4; ++j) {
                hh[j] = (e + j < e1) ? h_id[e + j] : 0;
                tt[j] = (e + j < e1) ? t_id[e + j] : 0;
            }
        }
#pragma unroll
        for (int j = 0; j < 4; ++j) {
            if (e + j >= e1) break;
            int h = hh[j], t = tt[j];
            int rt = t - n0;
            if ((unsigned)rt < (unsigned)rlen) {
                float2 v = *(const float2*)&pef1[2 * (size_t)h];
                atomicAdd(&bins[0][rt], v.x);
                atomicAdd(&bins[1][rt], v.y);
            }
            int rh = h - n0;
            if ((unsigned)rh < (unsigned)rlen) {
                float2 v = *(const float2*)&per1[2 * (size_t)t];
                atomicAdd(&bins[2][rh], v.x);
                atomicAdd(&bins[3][rh], v.y);
            }
        }
    }
    __syncthreads();
#pragma unroll
    for (int c = 0; c < 4; ++c)
        for (int r = tid; r < rlen; r += 256)
            part[((size_t)ec * 4 + c) * N + n0 + r] = bins[c][r];
}

__global__ __launch_bounds__(256) void reduce2_kernel(
        const float* __restrict__ part,
        const float* __restrict__ inv_fwd, const float* __restrict__ inv_rev,
        float* __restrict__ pef2, float* __restrict__ per2, int N) {
    int n = blockIdx.x * blockDim.x + threadIdx.x;
    if (n >= N) return;
    float s[4] = {0.f, 0.f, 0.f, 0.f};
#pragma unroll
    for (int ec = 0; ec < ECN; ++ec)
#pragma unroll
        for (int c = 0; c < 4; ++c)
            s[c] += part[((size_t)ec * 4 + c) * N + n];
    float invf = inv_fwd[n], invr = inv_rev[n];
    pef2[2 * n] = s[0] * invf;
    pef2[2 * n + 1] = s[1] * invf;
    per2[2 * n] = s[2] * invr;
    per2[2 * n + 1] = s[3] * invr;
}

// bias3[i][j] = b1[j] + intent[i]·W1[0:128][j] + q·W1[128:256][j]  (fp32)
__global__ void bias_kernel(const float* __restrict__ intent, const float* __restrict__ q,
                            const float* __restrict__ W1, const float* __restrict__ b1,
                            float* __restrict__ bias3) {
    int i = blockIdx.x;
    int j = threadIdx.x;
    float acc = b1[j];
#pragma unroll 4
    for (int k = 0; k < E; ++k) acc += intent[i * E + k] * W1[k * E + j];
#pragma unroll 4
    for (int k = 0; k < E; ++k) acc += q[k] * W1[(OFF_Q + k) * E + j];
    bias3[i * E + j] = acc;
}

// rel_pre (bf16)
__global__ __launch_bounds__(256) void relpre_kernel(
        const float* __restrict__ rel, const float* __restrict__ W1,
        unsigned short* __restrict__ rel_bf, int NREL) {
    int idx = blockIdx.x * blockDim.x + threadIdx.x;
    int r = idx >> 7, j = idx & 127;
    if (r >= NREL) return;
    const float4* xr = (const float4*)(rel + (size_t)r * E);
    float acc = 0.f;
#pragma unroll
    for (int k4 = 0; k4 < 32; ++k4) {
        float4 x = xr[k4];
        int k = OFF_REL + k4 * 4;
        acc = fmaf(x.x, W1[(k + 0) * E + j], acc);
        acc = fmaf(x.y, W1[(k + 1) * E + j], acc);
        acc = fmaf(x.z, W1[(k + 2) * E + j], acc);
        acc = fmaf(x.w, W1[(k + 3) * E + j], acc);
    }
    rel_bf[idx] = f2bf(acc);
}

// head/tail precompute via MFMA: [N x 160] @ [160 x 256] in bf16, fp32 acc.
// One 64-node tile per block; 4 waves; wave w owns cols 64w..64w+63.
// Frag layout (m89-verified): A row=lane&15, k=(lane>>4)*8+j;
// B col=lane&15, k=(lane>>4)*8+j; D col=lane&15, row=(lane>>4)*4+r.
__global__ __launch_bounds__(256) void nodepre_mfma(
        const float* __restrict__ ent, const float* __restrict__ nontext,
        const float* __restrict__ topic, const float* __restrict__ f1,
        const float* __restrict__ f2, const float* __restrict__ r1,
        const float* __restrict__ r2, const float* __restrict__ W1,
        unsigned short* __restrict__ head_bf, unsigned short* __restrict__ tail_bf,
        int N, int NTEXT) {
    __shared__ unsigned short As[64 * AST];
    int t = threadIdx.x;
    int lane = t & 63;
    int w = t >> 6;
    int l15 = lane & 15;
    int lg = lane >> 4;
    int n0 = blockIdx.x * 64;

    // ---- stage A tile: rows = nodes, k padded to 160, bf16 ----
    {
        int row = t >> 2, ch = t & 3;
        int node = n0 + row;
        bool ok = node < N;
        const float* src = (node < NTEXT) ? (ent + (size_t)node * E) : nontext;
        unsigned* dst = (unsigned*)&As[row * AST + ch * 32];
#pragma unroll
        for (int qq = 0; qq < 8; ++qq) {
            float4 v = ok ? *(const float4*)(src + ch * 32 + qq * 4)
                          : make_float4(0.f, 0.f, 0.f, 0.f);
            dst[qq * 2 + 0] = bpack(v.x, v.y);
            dst[qq * 2 + 1] = bpack(v.z, v.w);
        }
    }
    if (t < 64) {
        int node = n0 + t;
        bool ok = node < N;
        unsigned short* dst = &As[t * AST + 128];
        float ex[10];
        if (ok) {
            ex[0] = topic[2 * (size_t)node]; ex[1] = topic[2 * (size_t)node + 1];
            ex[2] = f1[2 * (size_t)node];    ex[3] = f1[2 * (size_t)node + 1];
            ex[4] = f2[2 * (size_t)node];    ex[5] = f2[2 * (size_t)node + 1];
            ex[6] = r1[2 * (size_t)node];    ex[7] = r1[2 * (size_t)node + 1];
            ex[8] = r2[2 * (size_t)node];    ex[9] = r2[2 * (size_t)node + 1];
        } else {
#pragma unroll
            for (int m = 0; m < 10; ++m) ex[m] = 0.f;
        }
#pragma unroll
        for (int m = 0; m < 10; ++m) dst[m] = f2bf(ex[m]);
#pragma unroll
        for (int m = 10; m < 32; ++m) dst[m] = 0;   // zero k = 138..159
    }

    // ---- load B frags (overlaps with staging; sync below) ----
    short8 bfrag[4][5];
#pragma unroll
    for (int ct = 0; ct < 4; ++ct) {
        int c = w * 64 + ct * 16 + l15;
        const float* wcol = (c < 128) ? (W1 + (size_t)OFF_HEAD * E + c)
                                      : (W1 + (size_t)OFF_TAIL * E + (c - 128));
#pragma unroll
        for (int ks = 0; ks < 5; ++ks) {
            int kbase = ks * 32 + lg * 8;
            union { short8 v; unsigned short u[8]; } bb;
#pragma unroll
            for (int j = 0; j < 8; ++j) {
                int k = kbase + j;
                float x = (k < KTOT) ? wcol[(size_t)k * E] : 0.f;
                bb.u[j] = f2bf(x);
            }
            bfrag[ct][ks] = bb.v;
        }
    }
    __syncthreads();

    // ---- MFMA ----
    f32x4 zero = {0.f, 0.f, 0.f, 0.f};
    f32x4 acc[4][4];
#pragma unroll
    for (int rt = 0; rt < 4; ++rt)
#pragma unroll
        for (int ct = 0; ct < 4; ++ct) acc[rt][ct] = zero;

#pragma unroll
    for (int ks = 0; ks < 5; ++ks) {
        short8 afrag[4];
#pragma unroll
        for (int rt = 0; rt < 4; ++rt) {
            int row = rt * 16 + l15;
            int kb = ks * 32 + lg * 8;
            afrag[rt] = *(const short8*)&As[row * AST + kb];
        }
#pragma unroll
        for (int ct = 0; ct < 4; ++ct)
#pragma unroll
            for (int rt = 0; rt < 4; ++rt)
                acc[rt][ct] = __builtin_amdgcn_mfma_f32_16x16x32_bf16(
                    afrag[rt], bfrag[ct][ks], acc[rt][ct], 0, 0, 0);
    }

    // ---- write C as bf16 ----
#pragma unroll
    for (int rt = 0; rt < 4; ++rt) {
#pragma unroll
        for (int ct = 0; ct < 4; ++ct) {
            int c = w * 64 + ct * 16 + l15;
            unsigned short* base = (c < 128) ? head_bf : tail_bf;
            int cc = (c < 128) ? c : c - 128;
#pragma unroll
            for (int r = 0; r < 4; ++r) {
                int node = n0 + rt * 16 + lg * 4 + r;
                if (node < N) base[(size_t)node * E + cc] = f2bf(acc[rt][ct][r]);
            }
        }
    }
}

// 16 lanes per edge, 4 edges per wave; bf16 table gathers
__global__ __launch_bounds__(256) void edge_kernel(
        const int* __restrict__ h_id, const int* __restrict__ r_id, const int* __restrict__ t_id,
        const unsigned short* __restrict__ head_bf, const unsigned short* __restrict__ rel_bf,
        const unsigned short* __restrict__ tail_bf, const float* __restrict__ bias3,
        const float* __restrict__ W2, const float* __restrict__ b2,
        float* __restrict__ out, int T) {
    int lane = threadIdx.x & 63;
    int sub = lane >> 4;
    int sl = lane & 15;
    int wid = blockIdx.x * (blockDim.x >> 6) + (threadIdx.x >> 6);
    int nw = gridDim.x * (blockDim.x >> 6);
    int c0 = sl * 8;

    float4 bi0a = *(const float4*)&bias3[c0],         bi0b = *(const float4*)&bias3[c0 + 4];
    float4 bi1a = *(const float4*)&bias3[E + c0],     bi1b = *(const float4*)&bias3[E + c0 + 4];
    float4 bi2a = *(const float4*)&bias3[2 * E + c0], bi2b = *(const float4*)&bias3[2 * E + c0 + 4];
    float4 w2a = *(const float4*)&W2[c0], w2b = *(const float4*)&W2[c0 + 4];
    float b2s = b2[0];

    int ne4 = (T + 3) >> 2;
    for (int e4 = wid; e4 < ne4; e4 += nw) {
        int e = e4 * 4 + sub;
        float p0 = 0.f, p1 = 0.f, p2 = 0.f;
        if (e < T) {
            int h = h_id[e], r = r_id[e], tt = t_id[e];
            uint4 hu = *(const uint4*)(head_bf + (size_t)h * E + c0);
            uint4 ru = *(const uint4*)(rel_bf + (size_t)r * E + c0);
            uint4 tu = *(const uint4*)(tail_bf + (size_t)tt * E + c0);
            float s[8];
            s[0] = blo(hu.x) + blo(ru.x) + blo(tu.x);
            s[1] = bhi(hu.x) + bhi(ru.x) + bhi(tu.x);
            s[2] = blo(hu.y) + blo(ru.y) + blo(tu.y);
            s[3] = bhi(hu.y) + bhi(ru.y) + bhi(tu.y);
            s[4] = blo(hu.z) + blo(ru.z) + blo(tu.z);
            s[5] = bhi(hu.z) + bhi(ru.z) + bhi(tu.z);
            s[6] = blo(hu.w) + blo(ru.w) + blo(tu.w);
            s[7] = bhi(hu.w) + bhi(ru.w) + bhi(tu.w);
            float bi0[8] = {bi0a.x, bi0a.y, bi0a.z, bi0a.w, bi0b.x, bi0b.y, bi0b.z, bi0b.w};
            float bi1[8] = {bi1a.x, bi1a.y, bi1a.z, bi1a.w, bi1b.x, bi1b.y, bi1b.z, bi1b.w};
            float bi2[8] = {bi2a.x, bi2a.y, bi2a.z, bi2a.w, bi2b.x, bi2b.y, bi2b.z, bi2b.w};
            float w2v[8] = {w2a.x, w2a.y, w2a.z, w2a.w, w2b.x, w2b.y, w2b.z, w2b.w};
#pragma unroll
            for (int j = 0; j < 8; ++j) {
                p0 = fmaf(fmaxf(s[j] + bi0[j], 0.f), w2v[j], p0);
                p1 = fmaf(fmaxf(s[j] + bi1[j], 0.f), w2v[j], p1);
                p2 = fmaf(fmaxf(s[j] + bi2[j], 0.f), w2v[j], p2);
            }
        }
#pragma unroll
        for (int o = 1; o < 16; o <<= 1) {
            p0 += __shfl_xor(p0, o, 64);
            p1 += __shfl_xor(p1, o, 64);
            p2 += __shfl_xor(p2, o, 64);
        }
        if (e < T && sl < 3) {
            float v = (sl == 0) ? p0 : ((sl == 1) ? p1 : p2);
            out[(size_t)e * 3 + sl] = v + b2s;
        }
    }
}

extern "C" void kernel_launch(void* const* d_in, const int* in_sizes, int n_in,
                              void* d_out, int out_size, void* d_ws, size_t ws_size,
                              hipStream_t stream) {
    const int* h_id = (const int*)d_in[0];
    const int* r_id = (const int*)d_in[1];
    const int* t_id = (const int*)d_in[2];
    const float* q = (const float*)d_in[3];
    const float* ent = (const float*)d_in[4];
    const float* rel = (const float*)d_in[6];
    const float* topic = (const float*)d_in[7];
    const float* nontext = (const float*)d_in[8];
    const float* intent = (const float*)d_in[9];
    const float* W1 = (const float*)d_in[10];
    const float* b1 = (const float*)d_in[11];
    const float* W2 = (const float*)d_in[12];
    const float* b2 = (const float*)d_in[13];

    int T = in_sizes[0];
    int NTEXT = in_sizes[4] / E;
    int N = in_sizes[7] / 2;
    int NREL = in_sizes[6] / E;

    float* ws = (float*)d_ws;
    float* inv_fwd = ws;                            // N
    float* inv_rev = ws + (size_t)N;                // N
    float* pef1 = ws + 2 * (size_t)N;               // 2N
    float* per1 = ws + 4 * (size_t)N;               // 2N
    float* pef2 = ws + 6 * (size_t)N;               // 2N
    float* per2 = ws + 8 * (size_t)N;               // 2N
    float* bias3 = ws + 10 * (size_t)N;             // 3*E = 384
    float* part = bias3 + 3 * E;                    // ECN*6*N floats
    float* after_part = part + (size_t)ECN * 6 * N;
    unsigned short* rel_bf = (unsigned short*)after_part;          // NREL*E bf16
    unsigned short* head_bf = rel_bf + (size_t)NREL * E;           // N*E bf16
    unsigned short* tail_bf = head_bf + (size_t)N * E;             // N*E bf16

    const int tb = 256;
    int RC = (N + RNG - 1) / RNG;
    int chunk = ((T + ECN - 1) / ECN + 3) & ~3;
    dim3 sg(RC, ECN);

    scat1_kernel<<<sg, tb, 0, stream>>>(h_id, t_id, topic, part, T, N, chunk);
    reduce1_kernel<<<(N + tb - 1) / tb, tb, 0, stream>>>(part, pef1, per1, inv_fwd, inv_rev, N);
    scat2_kernel<<<sg, tb, 0, stream>>>(h_id, t_id, pef1, per1, part, T, N, chunk);
    reduce2_kernel<<<(N + tb - 1) / tb, tb, 0, stream>>>(part, inv_fwd, inv_rev, pef2, per2, N);

    bias_kernel<<<3, E, 0, stream>>>(intent, q, W1, b1, bias3);
    relpre_kernel<<<(NREL * E + tb - 1) / tb, tb, 0, stream>>>(rel, W1, rel_bf, NREL);
    nodepre_mfma<<<(N + 63) / 64, tb, 0, stream>>>(ent, nontext, topic, pef1, pef2,
                                                   per1, per2, W1, head_bf, tail_bf,
                                                   N, NTEXT);
    edge_kernel<<<2048, tb, 0, stream>>>(h_id, r_id, t_id, head_bf, rel_bf, tail_bf,
                                         bias3, W2, b2, (float*)d_out, T);
}

// Round 6
// 177.222 us; speedup vs baseline: 2.3195x; 1.0547x over previous
//
#include <hip/hip_runtime.h>

#define E 128
#define OFF_Q 128
#define OFF_HEAD 256
#define OFF_REL 394
#define OFF_TAIL 522
#define KTOT 138      // 128 + 2 + 2*4
#define AST 168       // LDS A row stride in bf16 for nodepre
#define RNG 2560      // nodes per LDS range
#define ECN 32        // edge chunks

typedef __attribute__((ext_vector_type(8))) short short8;
typedef __attribute__((ext_vector_type(4))) float f32x4;

// ---- bf16 helpers (RNE, finite values only) ----
__device__ __forceinline__ unsigned short f2bf(float f) {
    unsigned u = __float_as_uint(f);
    return (unsigned short)((u + 0x7fffu + ((u >> 16) & 1u)) >> 16);
}
__device__ __forceinline__ unsigned bpack(float lo, float hi) {
    return (unsigned)f2bf(lo) | ((unsigned)f2bf(hi) << 16);
}
__device__ __forceinline__ float blo(unsigned u) { return __uint_as_float(u << 16); }
__device__ __forceinline__ float bhi(unsigned u) { return __uint_as_float(u & 0xffff0000u); }

// ---- round-1 scatter: per-(range,chunk) LDS binning; bf16 packed partials ----
__global__ __launch_bounds__(256) void scat1_kernel(
        const int* __restrict__ h_id, const int* __restrict__ t_id,
        const float* __restrict__ topic, unsigned* __restrict__ part,
        int T, int N, int chunk) {
    __shared__ float bins[6][RNG];
    int tid = threadIdx.x;
    int n0 = blockIdx.x * RNG;
    int rlen = min(RNG, N - n0);
    int ec = blockIdx.y;
    for (int i = tid; i < 6 * RNG; i += 256) ((float*)bins)[i] = 0.f;
    __syncthreads();
    int e0 = ec * chunk;
    int e1 = min(T, e0 + chunk);
    for (int e = e0 + tid * 8; e < e1; e += 256 * 8) {
        int hh[8], tt[8];
        if (e + 7 < e1) {
            int4 ha = *(const int4*)&h_id[e];
            int4 hb = *(const int4*)&h_id[e + 4];
            int4 ta = *(const int4*)&t_id[e];
            int4 tb = *(const int4*)&t_id[e + 4];
            hh[0]=ha.x; hh[1]=ha.y; hh[2]=ha.z; hh[3]=ha.w;
            hh[4]=hb.x; hh[5]=hb.y; hh[6]=hb.z; hh[7]=hb.w;
            tt[0]=ta.x; tt[1]=ta.y; tt[2]=ta.z; tt[3]=ta.w;
            tt[4]=tb.x; tt[5]=tb.y; tt[6]=tb.z; tt[7]=tb.w;
        } else {
#pragma unroll
            for (int j = 0; j < 8; ++j) {
                hh[j] = (e + j < e1) ? h_id[e + j] : 0;
                tt[j] = (e + j < e1) ? t_id[e + j] : 0;
            }
        }
#pragma unroll
        for (int j = 0; j < 8; ++j) {
            if (e + j >= e1) break;
            int h = hh[j], t = tt[j];
            int rt = t - n0;
            if ((unsigned)rt < (unsigned)rlen) {
                float2 v = *(const float2*)&topic[2 * (size_t)h];
                atomicAdd(&bins[0][rt], v.x);
                atomicAdd(&bins[1][rt], v.y);
                atomicAdd(&bins[2][rt], 1.0f);
            }
            int rh = h - n0;
            if ((unsigned)rh < (unsigned)rlen) {
                float2 v = *(const float2*)&topic[2 * (size_t)t];
                atomicAdd(&bins[3][rh], v.x);
                atomicAdd(&bins[4][rh], v.y);
                atomicAdd(&bins[5][rh], 1.0f);
            }
        }
    }
    __syncthreads();
    int NW = N >> 1;
    int p0 = n0 >> 1;
#pragma unroll
    for (int c = 0; c < 6; ++c)
        for (int r = tid * 2; r < rlen; r += 512)
            part[((size_t)ec * 6 + c) * NW + p0 + (r >> 1)] = bpack(bins[c][r], bins[c][r + 1]);
}

__global__ __launch_bounds__(256) void reduce1_kernel(
        const unsigned* __restrict__ part,
        float* __restrict__ pef1, float* __restrict__ per1,
        float* __restrict__ inv_fwd, float* __restrict__ inv_rev, int N) {
    int p = blockIdx.x * blockDim.x + threadIdx.x;
    int NW = N >> 1;
    if (p >= NW) return;
    float s[6][2];
#pragma unroll
    for (int c = 0; c < 6; ++c) { s[c][0] = 0.f; s[c][1] = 0.f; }
    for (int ec = 0; ec < ECN; ++ec)
#pragma unroll
        for (int c = 0; c < 6; ++c) {
            unsigned v = part[((size_t)ec * 6 + c) * NW + p];
            s[c][0] += blo(v);
            s[c][1] += bhi(v);
        }
#pragma unroll
    for (int u = 0; u < 2; ++u) {
        int n = 2 * p + u;
        float invf = 1.0f / fmaxf(s[2][u], 1.0f);
        float invr = 1.0f / fmaxf(s[5][u], 1.0f);
        pef1[2 * n] = s[0][u] * invf;
        pef1[2 * n + 1] = s[1][u] * invf;
        per1[2 * n] = s[3][u] * invr;
        per1[2 * n + 1] = s[4][u] * invr;
        inv_fwd[n] = invf;
        inv_rev[n] = invr;
    }
}

__global__ __launch_bounds__(256) void scat2_kernel(
        const int* __restrict__ h_id, const int* __restrict__ t_id,
        const float* __restrict__ pef1, const float* __restrict__ per1,
        unsigned* __restrict__ part, int T, int N, int chunk) {
    __shared__ float bins[4][RNG];
    int tid = threadIdx.x;
    int n0 = blockIdx.x * RNG;
    int rlen = min(RNG, N - n0);
    int ec = blockIdx.y;
    for (int i = tid; i < 4 * RNG; i += 256) ((float*)bins)[i] = 0.f;
    __syncthreads();
    int e0 = ec * chunk;
    int e1 = min(T, e0 + chunk);
    for (int e = e0 + tid * 8; e < e1; e += 256 * 8) {
        int hh[8], tt[8];
        if (e + 7 < e1) {
            int4 ha = *(const int4*)&h_id[e];
            int4 hb = *(const int4*)&h_id[e + 4];
            int4 ta = *(const int4*)&t_id[e];
            int4 tb = *(const int4*)&t_id[e + 4];
            hh[0]=ha.x; hh[1]=ha.y; hh[2]=ha.z; hh[3]=ha.w;
            hh[4]=hb.x; hh[5]=hb.y; hh[6]=hb.z; hh[7]=hb.w;
            tt[0]=ta.x; tt[1]=ta.y; tt[2]=ta.z; tt[3]=ta.w;
            tt[4]=tb.x; tt[5]=tb.y; tt[6]=tb.z; tt[7]=tb.w;
        } else {
#pragma unroll
            for (int j = 0; j < 8; ++j) {
                hh[j] = (e + j < e1) ? h_id[e + j] : 0;
                tt[j] = (e + j < e1) ? t_id[e + j] : 0;
            }
        }
#pragma unroll
        for (int j = 0; j < 8; ++j) {
            if (e + j >= e1) break;
            int h = hh[j], t = tt[j];
            int rt = t - n0;
            if ((unsigned)rt < (unsigned)rlen) {
                float2 v = *(const float2*)&pef1[2 * (size_t)h];
                atomicAdd(&bins[0][rt], v.x);
                atomicAdd(&bins[1][rt], v.y);
            }
            int rh = h - n0;
            if ((unsigned)rh < (unsigned)rlen) {
                float2 v = *(const float2*)&per1[2 * (size_t)t];
                atomicAdd(&bins[2][rh], v.x);
                atomicAdd(&bins[3][rh], v.y);
            }
        }
    }
    __syncthreads();
    int NW = N >> 1;
    int p0 = n0 >> 1;
#pragma unroll
    for (int c = 0; c < 4; ++c)
        for (int r = tid * 2; r < rlen; r += 512)
            part[((size_t)ec * 4 + c) * NW + p0 + (r >> 1)] = bpack(bins[c][r], bins[c][r + 1]);
}

__global__ __launch_bounds__(256) void reduce2_kernel(
        const unsigned* __restrict__ part,
        const float* __restrict__ inv_fwd, const float* __restrict__ inv_rev,
        float* __restrict__ pef2, float* __restrict__ per2, int N) {
    int p = blockIdx.x * blockDim.x + threadIdx.x;
    int NW = N >> 1;
    if (p >= NW) return;
    float s[4][2];
#pragma unroll
    for (int c = 0; c < 4; ++c) { s[c][0] = 0.f; s[c][1] = 0.f; }
    for (int ec = 0; ec < ECN; ++ec)
#pragma unroll
        for (int c = 0; c < 4; ++c) {
            unsigned v = part[((size_t)ec * 4 + c) * NW + p];
            s[c][0] += blo(v);
            s[c][1] += bhi(v);
        }
#pragma unroll
    for (int u = 0; u < 2; ++u) {
        int n = 2 * p + u;
        float invf = inv_fwd[n], invr = inv_rev[n];
        pef2[2 * n] = s[0][u] * invf;
        pef2[2 * n + 1] = s[1][u] * invf;
        per2[2 * n] = s[2][u] * invr;
        per2[2 * n + 1] = s[3][u] * invr;
    }
}

// bias3[i][j] = b1[j] + intent[i]·W1[0:128][j] + q·W1[128:256][j]  (fp32)
__global__ void bias_kernel(const float* __restrict__ intent, const float* __restrict__ q,
                            const float* __restrict__ W1, const float* __restrict__ b1,
                            float* __restrict__ bias3) {
    int i = blockIdx.x;
    int j = threadIdx.x;
    float acc = b1[j];
#pragma unroll 4
    for (int k = 0; k < E; ++k) acc += intent[i * E + k] * W1[k * E + j];
#pragma unroll 4
    for (int k = 0; k < E; ++k) acc += q[k] * W1[(OFF_Q + k) * E + j];
    bias3[i * E + j] = acc;
}

// rel_pre (bf16)
__global__ __launch_bounds__(256) void relpre_kernel(
        const float* __restrict__ rel, const float* __restrict__ W1,
        unsigned short* __restrict__ rel_bf, int NREL) {
    int idx = blockIdx.x * blockDim.x + threadIdx.x;
    int r = idx >> 7, j = idx & 127;
    if (r >= NREL) return;
    const float4* xr = (const float4*)(rel + (size_t)r * E);
    float acc = 0.f;
#pragma unroll
    for (int k4 = 0; k4 < 32; ++k4) {
        float4 x = xr[k4];
        int k = OFF_REL + k4 * 4;
        acc = fmaf(x.x, W1[(k + 0) * E + j], acc);
        acc = fmaf(x.y, W1[(k + 1) * E + j], acc);
        acc = fmaf(x.z, W1[(k + 2) * E + j], acc);
        acc = fmaf(x.w, W1[(k + 3) * E + j], acc);
    }
    rel_bf[idx] = f2bf(acc);
}

// head/tail precompute via MFMA: [N x 160] @ [160 x 256] in bf16, fp32 acc.
__global__ __launch_bounds__(256) void nodepre_mfma(
        const float* __restrict__ ent, const float* __restrict__ nontext,
        const float* __restrict__ topic, const float* __restrict__ f1,
        const float* __restrict__ f2, const float* __restrict__ r1,
        const float* __restrict__ r2, const float* __restrict__ W1,
        unsigned short* __restrict__ head_bf, unsigned short* __restrict__ tail_bf,
        int N, int NTEXT) {
    __shared__ unsigned short As[64 * AST];
    int t = threadIdx.x;
    int lane = t & 63;
    int w = t >> 6;
    int l15 = lane & 15;
    int lg = lane >> 4;
    int n0 = blockIdx.x * 64;

    {
        int row = t >> 2, ch = t & 3;
        int node = n0 + row;
        bool ok = node < N;
        const float* src = (node < NTEXT) ? (ent + (size_t)node * E) : nontext;
        unsigned* dst = (unsigned*)&As[row * AST + ch * 32];
#pragma unroll
        for (int qq = 0; qq < 8; ++qq) {
            float4 v = ok ? *(const float4*)(src + ch * 32 + qq * 4)
                          : make_float4(0.f, 0.f, 0.f, 0.f);
            dst[qq * 2 + 0] = bpack(v.x, v.y);
            dst[qq * 2 + 1] = bpack(v.z, v.w);
        }
    }
    if (t < 64) {
        int node = n0 + t;
        bool ok = node < N;
        unsigned short* dst = &As[t * AST + 128];
        float ex[10];
        if (ok) {
            ex[0] = topic[2 * (size_t)node]; ex[1] = topic[2 * (size_t)node + 1];
            ex[2] = f1[2 * (size_t)node];    ex[3] = f1[2 * (size_t)node + 1];
            ex[4] = f2[2 * (size_t)node];    ex[5] = f2[2 * (size_t)node + 1];
            ex[6] = r1[2 * (size_t)node];    ex[7] = r1[2 * (size_t)node + 1];
            ex[8] = r2[2 * (size_t)node];    ex[9] = r2[2 * (size_t)node + 1];
        } else {
#pragma unroll
            for (int m = 0; m < 10; ++m) ex[m] = 0.f;
        }
#pragma unroll
        for (int m = 0; m < 10; ++m) dst[m] = f2bf(ex[m]);
#pragma unroll
        for (int m = 10; m < 32; ++m) dst[m] = 0;
    }

    short8 bfrag[4][5];
#pragma unroll
    for (int ct = 0; ct < 4; ++ct) {
        int c = w * 64 + ct * 16 + l15;
        const float* wcol = (c < 128) ? (W1 + (size_t)OFF_HEAD * E + c)
                                      : (W1 + (size_t)OFF_TAIL * E + (c - 128));
#pragma unroll
        for (int ks = 0; ks < 5; ++ks) {
            int kbase = ks * 32 + lg * 8;
            union { short8 v; unsigned short u[8]; } bb;
#pragma unroll
            for (int j = 0; j < 8; ++j) {
                int k = kbase + j;
                float x = (k < KTOT) ? wcol[(size_t)k * E] : 0.f;
                bb.u[j] = f2bf(x);
            }
            bfrag[ct][ks] = bb.v;
        }
    }
    __syncthreads();

    f32x4 zero = {0.f, 0.f, 0.f, 0.f};
    f32x4 acc[4][4];
#pragma unroll
    for (int rt = 0; rt < 4; ++rt)
#pragma unroll
        for (int ct = 0; ct < 4; ++ct) acc[rt][ct] = zero;

#pragma unroll
    for (int ks = 0; ks < 5; ++ks) {
        short8 afrag[4];
#pragma unroll
        for (int rt = 0; rt < 4; ++rt) {
            int row = rt * 16 + l15;
            int kb = ks * 32 + lg * 8;
            afrag[rt] = *(const short8*)&As[row * AST + kb];
        }
#pragma unroll
        for (int ct = 0; ct < 4; ++ct)
#pragma unroll
            for (int rt = 0; rt < 4; ++rt)
                acc[rt][ct] = __builtin_amdgcn_mfma_f32_16x16x32_bf16(
                    afrag[rt], bfrag[ct][ks], acc[rt][ct], 0, 0, 0);
    }

#pragma unroll
    for (int rt = 0; rt < 4; ++rt) {
#pragma unroll
        for (int ct = 0; ct < 4; ++ct) {
            int c = w * 64 + ct * 16 + l15;
            unsigned short* base = (c < 128) ? head_bf : tail_bf;
            int cc = (c < 128) ? c : c - 128;
#pragma unroll
            for (int r = 0; r < 4; ++r) {
                int node = n0 + rt * 16 + lg * 4 + r;
                if (node < N) base[(size_t)node * E + cc] = f2bf(acc[rt][ct][r]);
            }
        }
    }
}

// 16 lanes per edge, 4 edges per wave; bf16 table gathers
__global__ __launch_bounds__(256) void edge_kernel(
        const int* __restrict__ h_id, const int* __restrict__ r_id, const int* __restrict__ t_id,
        const unsigned short* __restrict__ head_bf, const unsigned short* __restrict__ rel_bf,
        const unsigned short* __restrict__ tail_bf, const float* __restrict__ bias3,
        const float* __restrict__ W2, const float* __restrict__ b2,
        float* __restrict__ out, int T) {
    int lane = threadIdx.x & 63;
    int sub = lane >> 4;
    int sl = lane & 15;
    int wid = blockIdx.x * (blockDim.x >> 6) + (threadIdx.x >> 6);
    int nw = gridDim.x * (blockDim.x >> 6);
    int c0 = sl * 8;

    float4 bi0a = *(const float4*)&bias3[c0],         bi0b = *(const float4*)&bias3[c0 + 4];
    float4 bi1a = *(const float4*)&bias3[E + c0],     bi1b = *(const float4*)&bias3[E + c0 + 4];
    float4 bi2a = *(const float4*)&bias3[2 * E + c0], bi2b = *(const float4*)&bias3[2 * E + c0 + 4];
    float4 w2a = *(const float4*)&W2[c0], w2b = *(const float4*)&W2[c0 + 4];
    float b2s = b2[0];

    int ne4 = (T + 3) >> 2;
    for (int e4 = wid; e4 < ne4; e4 += nw) {
        int e = e4 * 4 + sub;
        float p0 = 0.f, p1 = 0.f, p2 = 0.f;
        if (e < T) {
            int h = h_id[e], r = r_id[e], tt = t_id[e];
            uint4 hu = *(const uint4*)(head_bf + (size_t)h * E + c0);
            uint4 ru = *(const uint4*)(rel_bf + (size_t)r * E + c0);
            uint4 tu = *(const uint4*)(tail_bf + (size_t)tt * E + c0);
            float s[8];
            s[0] = blo(hu.x) + blo(ru.x) + blo(tu.x);
            s[1] = bhi(hu.x) + bhi(ru.x) + bhi(tu.x);
            s[2] = blo(hu.y) + blo(ru.y) + blo(tu.y);
            s[3] = bhi(hu.y) + bhi(ru.y) + bhi(tu.y);
            s[4] = blo(hu.z) + blo(ru.z) + blo(tu.z);
            s[5] = bhi(hu.z) + bhi(ru.z) + bhi(tu.z);
            s[6] = blo(hu.w) + blo(ru.w) + blo(tu.w);
            s[7] = bhi(hu.w) + bhi(ru.w) + bhi(tu.w);
            float bi0[8] = {bi0a.x, bi0a.y, bi0a.z, bi0a.w, bi0b.x, bi0b.y, bi0b.z, bi0b.w};
            float bi1[8] = {bi1a.x, bi1a.y, bi1a.z, bi1a.w, bi1b.x, bi1b.y, bi1b.z, bi1b.w};
            float bi2[8] = {bi2a.x, bi2a.y, bi2a.z, bi2a.w, bi2b.x, bi2b.y, bi2b.z, bi2b.w};
            float w2v[8] = {w2a.x, w2a.y, w2a.z, w2a.w, w2b.x, w2b.y, w2b.z, w2b.w};
#pragma unroll
            for (int j = 0; j < 8; ++j) {
                p0 = fmaf(fmaxf(s[j] + bi0[j], 0.f), w2v[j], p0);
                p1 = fmaf(fmaxf(s[j] + bi1[j], 0.f), w2v[j], p1);
                p2 = fmaf(fmaxf(s[j] + bi2[j], 0.f), w2v[j], p2);
            }
        }
#pragma unroll
        for (int o = 1; o < 16; o <<= 1) {
            p0 += __shfl_xor(p0, o, 64);
            p1 += __shfl_xor(p1, o, 64);
            p2 += __shfl_xor(p2, o, 64);
        }
        if (e < T && sl < 3) {
            float v = (sl == 0) ? p0 : ((sl == 1) ? p1 : p2);
            out[(size_t)e * 3 + sl] = v + b2s;
        }
    }
}

extern "C" void kernel_launch(void* const* d_in, const int* in_sizes, int n_in,
                              void* d_out, int out_size, void* d_ws, size_t ws_size,
                              hipStream_t stream) {
    const int* h_id = (const int*)d_in[0];
    const int* r_id = (const int*)d_in[1];
    const int* t_id = (const int*)d_in[2];
    const float* q = (const float*)d_in[3];
    const float* ent = (const float*)d_in[4];
    const float* rel = (const float*)d_in[6];
    const float* topic = (const float*)d_in[7];
    const float* nontext = (const float*)d_in[8];
    const float* intent = (const float*)d_in[9];
    const float* W1 = (const float*)d_in[10];
    const float* b1 = (const float*)d_in[11];
    const float* W2 = (const float*)d_in[12];
    const float* b2 = (const float*)d_in[13];

    int T = in_sizes[0];
    int NTEXT = in_sizes[4] / E;
    int N = in_sizes[7] / 2;
    int NREL = in_sizes[6] / E;

    float* ws = (float*)d_ws;
    float* inv_fwd = ws;                            // N
    float* inv_rev = ws + (size_t)N;                // N
    float* pef1 = ws + 2 * (size_t)N;               // 2N
    float* per1 = ws + 4 * (size_t)N;               // 2N
    float* pef2 = ws + 6 * (size_t)N;               // 2N
    float* per2 = ws + 8 * (size_t)N;               // 2N
    float* bias3 = ws + 10 * (size_t)N;             // 3*E = 384
    unsigned* part = (unsigned*)(bias3 + 3 * E);    // ECN*6*(N/2) u32
    float* after_part = (float*)(part + (size_t)ECN * 6 * (N / 2));
    unsigned short* rel_bf = (unsigned short*)after_part;          // NREL*E bf16
    unsigned short* head_bf = rel_bf + (size_t)NREL * E;           // N*E bf16
    unsigned short* tail_bf = head_bf + (size_t)N * E;             // N*E bf16

    const int tb = 256;
    int RC = (N + RNG - 1) / RNG;
    int chunk = ((T + ECN - 1) / ECN + 7) & ~7;
    dim3 sg(RC, ECN);
    int NW = N / 2;

    scat1_kernel<<<sg, tb, 0, stream>>>(h_id, t_id, topic, part, T, N, chunk);
    reduce1_kernel<<<(NW + tb - 1) / tb, tb, 0, stream>>>(part, pef1, per1, inv_fwd, inv_rev, N);
    scat2_kernel<<<sg, tb, 0, stream>>>(h_id, t_id, pef1, per1, part, T, N, chunk);
    reduce2_kernel<<<(NW + tb - 1) / tb, tb, 0, stream>>>(part, inv_fwd, inv_rev, pef2, per2, N);

    bias_kernel<<<3, E, 0, stream>>>(intent, q, W1, b1, bias3);
    relpre_kernel<<<(NREL * E + tb - 1) / tb, tb, 0, stream>>>(rel, W1, rel_bf, NREL);
    nodepre_mfma<<<(N + 63) / 64, tb, 0, stream>>>(ent, nontext, topic, pef1, pef2,
                                                   per1, per2, W1, head_bf, tail_bf,
                                                   N, NTEXT);
    edge_kernel<<<2048, tb, 0, stream>>>(h_id, r_id, t_id, head_bf, rel_bf, tail_bf,
                                         bias3, W2, b2, (float*)d_out, T);
}

// Round 7
// 158.408 us; speedup vs baseline: 2.5950x; 1.1188x over previous
//
#include <hip/hip_runtime.h>

#define E 128
#define OFF_Q 128
#define OFF_HEAD 256
#define OFF_REL 394
#define OFF_TAIL 522
#define KTOT 138      // 128 + 2 + 2*4
#define AST 168       // LDS A row stride in bf16 for nodepre
#define RNG1 2048     // nodes per LDS range, scat1 (6ch*2048*4 = 48KB -> 3 blk/CU)
#define RNG2 3072     // nodes per LDS range, scat2 (4ch*3072*4 = 48KB -> 3 blk/CU)
#define ECN 32        // edge chunks

typedef __attribute__((ext_vector_type(8))) short short8;
typedef __attribute__((ext_vector_type(4))) float f32x4;

// ---- bf16 helpers (RNE, finite values only) ----
__device__ __forceinline__ unsigned short f2bf(float f) {
    unsigned u = __float_as_uint(f);
    return (unsigned short)((u + 0x7fffu + ((u >> 16) & 1u)) >> 16);
}
__device__ __forceinline__ unsigned bpack(float lo, float hi) {
    return (unsigned)f2bf(lo) | ((unsigned)f2bf(hi) << 16);
}
__device__ __forceinline__ float blo(unsigned u) { return __uint_as_float(u << 16); }
__device__ __forceinline__ float bhi(unsigned u) { return __uint_as_float(u & 0xffff0000u); }

// ---- fused: scat1 (LDS-binned, bf16 packed partials) + relpre + bias ----
__global__ __launch_bounds__(256) void fused1_kernel(
        const int* __restrict__ h_id, const int* __restrict__ t_id,
        const float* __restrict__ topic, const float* __restrict__ rel,
        const float* __restrict__ intent, const float* __restrict__ q,
        const float* __restrict__ W1, const float* __restrict__ b1,
        unsigned* __restrict__ part, unsigned short* __restrict__ rel_bf,
        float* __restrict__ bias3,
        int T, int N, int chunk, int RC1, int scatBlocks, int relBlocks, int NREL) {
    __shared__ float bins[6][RNG1];
    int tid = threadIdx.x;
    int bid = blockIdx.x;

    if (bid < scatBlocks) {
        int rangeIdx = bid % RC1;
        int ec = bid / RC1;
        int n0 = rangeIdx * RNG1;
        int rlen = min(RNG1, N - n0);
        for (int i = tid; i < 6 * RNG1; i += 256) ((float*)bins)[i] = 0.f;
        __syncthreads();
        int e0 = ec * chunk;
        int e1 = min(T, e0 + chunk);
        for (int e = e0 + tid * 8; e < e1; e += 256 * 8) {
            int hh[8], tt[8];
            if (e + 7 < e1) {
                int4 ha = *(const int4*)&h_id[e];
                int4 hb = *(const int4*)&h_id[e + 4];
                int4 ta = *(const int4*)&t_id[e];
                int4 tb = *(const int4*)&t_id[e + 4];
                hh[0]=ha.x; hh[1]=ha.y; hh[2]=ha.z; hh[3]=ha.w;
                hh[4]=hb.x; hh[5]=hb.y; hh[6]=hb.z; hh[7]=hb.w;
                tt[0]=ta.x; tt[1]=ta.y; tt[2]=ta.z; tt[3]=ta.w;
                tt[4]=tb.x; tt[5]=tb.y; tt[6]=tb.z; tt[7]=tb.w;
            } else {
#pragma unroll
                for (int j = 0; j < 8; ++j) {
                    hh[j] = (e + j < e1) ? h_id[e + j] : 0;
                    tt[j] = (e + j < e1) ? t_id[e + j] : 0;
                }
            }
#pragma unroll
            for (int j = 0; j < 8; ++j) {
                if (e + j >= e1) break;
                int h = hh[j], t = tt[j];
                int rt = t - n0;
                if ((unsigned)rt < (unsigned)rlen) {
                    float2 v = *(const float2*)&topic[2 * (size_t)h];
                    atomicAdd(&bins[0][rt], v.x);
                    atomicAdd(&bins[1][rt], v.y);
                    atomicAdd(&bins[2][rt], 1.0f);
                }
                int rh = h - n0;
                if ((unsigned)rh < (unsigned)rlen) {
                    float2 v = *(const float2*)&topic[2 * (size_t)t];
                    atomicAdd(&bins[3][rh], v.x);
                    atomicAdd(&bins[4][rh], v.y);
                    atomicAdd(&bins[5][rh], 1.0f);
                }
            }
        }
        __syncthreads();
        int NW = N >> 1;
        int p0 = n0 >> 1;
#pragma unroll
        for (int c = 0; c < 6; ++c)
            for (int r = tid * 2; r < rlen; r += 512)
                part[((size_t)ec * 6 + c) * NW + p0 + (r >> 1)] = bpack(bins[c][r], bins[c][r + 1]);
    } else if (bid < scatBlocks + relBlocks) {
        // ---- relpre: rel_bf[r][j] = rel[r]·W1[OFF_REL+ :][j] ----
        int idx = (bid - scatBlocks) * 256 + tid;
        int r = idx >> 7, j = idx & 127;
        if (r < NREL) {
            const float4* xr = (const float4*)(rel + (size_t)r * E);
            float acc = 0.f;
#pragma unroll
            for (int k4 = 0; k4 < 32; ++k4) {
                float4 x = xr[k4];
                int k = OFF_REL + k4 * 4;
                acc = fmaf(x.x, W1[(k + 0) * E + j], acc);
                acc = fmaf(x.y, W1[(k + 1) * E + j], acc);
                acc = fmaf(x.z, W1[(k + 2) * E + j], acc);
                acc = fmaf(x.w, W1[(k + 3) * E + j], acc);
            }
            rel_bf[idx] = f2bf(acc);
        }
    } else {
        // ---- bias3[i][j] = b1[j] + intent[i]·W1[0:128][j] + q·W1[128:256][j] ----
        int idx = (bid - scatBlocks - relBlocks) * 256 + tid;
        int i = idx >> 7, j = idx & 127;
        if (i < 3) {
            float acc = b1[j];
#pragma unroll 4
            for (int k = 0; k < E; ++k) acc += intent[i * E + k] * W1[k * E + j];
#pragma unroll 4
            for (int k = 0; k < E; ++k) acc += q[k] * W1[(OFF_Q + k) * E + j];
            bias3[i * E + j] = acc;
        }
    }
}

__global__ __launch_bounds__(256) void reduce1_kernel(
        const unsigned* __restrict__ part,
        float* __restrict__ pef1, float* __restrict__ per1,
        float* __restrict__ inv_fwd, float* __restrict__ inv_rev, int N) {
    int p = blockIdx.x * blockDim.x + threadIdx.x;
    int NW = N >> 1;
    if (p >= NW) return;
    float s[6][2];
#pragma unroll
    for (int c = 0; c < 6; ++c) { s[c][0] = 0.f; s[c][1] = 0.f; }
    for (int ec = 0; ec < ECN; ++ec)
#pragma unroll
        for (int c = 0; c < 6; ++c) {
            unsigned v = part[((size_t)ec * 6 + c) * NW + p];
            s[c][0] += blo(v);
            s[c][1] += bhi(v);
        }
#pragma unroll
    for (int u = 0; u < 2; ++u) {
        int n = 2 * p + u;
        float invf = 1.0f / fmaxf(s[2][u], 1.0f);
        float invr = 1.0f / fmaxf(s[5][u], 1.0f);
        pef1[2 * n] = s[0][u] * invf;
        pef1[2 * n + 1] = s[1][u] * invf;
        per1[2 * n] = s[3][u] * invr;
        per1[2 * n + 1] = s[4][u] * invr;
        inv_fwd[n] = invf;
        inv_rev[n] = invr;
    }
}

__global__ __launch_bounds__(256) void scat2_kernel(
        const int* __restrict__ h_id, const int* __restrict__ t_id,
        const float* __restrict__ pef1, const float* __restrict__ per1,
        unsigned* __restrict__ part, int T, int N, int chunk) {
    __shared__ float bins[4][RNG2];
    int tid = threadIdx.x;
    int n0 = blockIdx.x * RNG2;
    int rlen = min(RNG2, N - n0);
    int ec = blockIdx.y;
    for (int i = tid; i < 4 * RNG2; i += 256) ((float*)bins)[i] = 0.f;
    __syncthreads();
    int e0 = ec * chunk;
    int e1 = min(T, e0 + chunk);
    for (int e = e0 + tid * 8; e < e1; e += 256 * 8) {
        int hh[8], tt[8];
        if (e + 7 < e1) {
            int4 ha = *(const int4*)&h_id[e];
            int4 hb = *(const int4*)&h_id[e + 4];
            int4 ta = *(const int4*)&t_id[e];
            int4 tb = *(const int4*)&t_id[e + 4];
            hh[0]=ha.x; hh[1]=ha.y; hh[2]=ha.z; hh[3]=ha.w;
            hh[4]=hb.x; hh[5]=hb.y; hh[6]=hb.z; hh[7]=hb.w;
            tt[0]=ta.x; tt[1]=ta.y; tt[2]=ta.z; tt[3]=ta.w;
            tt[4]=tb.x; tt[5]=tb.y; tt[6]=tb.z; tt[7]=tb.w;
        } else {
#pragma unroll
            for (int j = 0; j < 8; ++j) {
                hh[j] = (e + j < e1) ? h_id[e + j] : 0;
                tt[j] = (e + j < e1) ? t_id[e + j] : 0;
            }
        }
#pragma unroll
        for (int j = 0; j < 8; ++j) {
            if (e + j >= e1) break;
            int h = hh[j], t = tt[j];
            int rt = t - n0;
            if ((unsigned)rt < (unsigned)rlen) {
                float2 v = *(const float2*)&pef1[2 * (size_t)h];
                atomicAdd(&bins[0][rt], v.x);
                atomicAdd(&bins[1][rt], v.y);
            }
            int rh = h - n0;
            if ((unsigned)rh < (unsigned)rlen) {
                float2 v = *(const float2*)&per1[2 * (size_t)t];
                atomicAdd(&bins[2][rh], v.x);
                atomicAdd(&bins[3][rh], v.y);
            }
        }
    }
    __syncthreads();
    int NW = N >> 1;
    int p0 = n0 >> 1;
#pragma unroll
    for (int c = 0; c < 4; ++c)
        for (int r = tid * 2; r < rlen; r += 512)
            part[((size_t)ec * 4 + c) * NW + p0 + (r >> 1)] = bpack(bins[c][r], bins[c][r + 1]);
}

// head/tail precompute via MFMA; pef2/per2 reduced inline from part2 partials.
__global__ __launch_bounds__(256) void nodepre_mfma(
        const float* __restrict__ ent, const float* __restrict__ nontext,
        const float* __restrict__ topic, const float* __restrict__ f1,
        const float* __restrict__ r1, const unsigned* __restrict__ part2,
        const float* __restrict__ inv_fwd, const float* __restrict__ inv_rev,
        const float* __restrict__ W1,
        unsigned short* __restrict__ head_bf, unsigned short* __restrict__ tail_bf,
        int N, int NTEXT) {
    __shared__ unsigned short As[64 * AST];
    int t = threadIdx.x;
    int lane = t & 63;
    int w = t >> 6;
    int l15 = lane & 15;
    int lg = lane >> 4;
    int n0 = blockIdx.x * 64;
    int NW = N >> 1;

    // ---- stage A tile rows (k<128) ----
    {
        int row = t >> 2, ch = t & 3;
        int node = n0 + row;
        bool ok = node < N;
        const float* src = (node < NTEXT) ? (ent + (size_t)node * E) : nontext;
        unsigned* dst = (unsigned*)&As[row * AST + ch * 32];
#pragma unroll
        for (int qq = 0; qq < 8; ++qq) {
            float4 v = ok ? *(const float4*)(src + ch * 32 + qq * 4)
                          : make_float4(0.f, 0.f, 0.f, 0.f);
            dst[qq * 2 + 0] = bpack(v.x, v.y);
            dst[qq * 2 + 1] = bpack(v.z, v.w);
        }
    }
    // ---- extras: topic(128,129) pef1(130,131) per1(134,135) + zero pad ----
    if (t < 64) {
        int node = n0 + t;
        bool ok = node < N;
        unsigned short* dst = &As[t * AST + 128];
        float ex[6];
        if (ok) {
            ex[0] = topic[2 * (size_t)node]; ex[1] = topic[2 * (size_t)node + 1];
            ex[2] = f1[2 * (size_t)node];    ex[3] = f1[2 * (size_t)node + 1];
            ex[4] = r1[2 * (size_t)node];    ex[5] = r1[2 * (size_t)node + 1];
        } else {
#pragma unroll
            for (int m = 0; m < 6; ++m) ex[m] = 0.f;
        }
        dst[0] = f2bf(ex[0]); dst[1] = f2bf(ex[1]);
        dst[2] = f2bf(ex[2]); dst[3] = f2bf(ex[3]);
        dst[6] = f2bf(ex[4]); dst[7] = f2bf(ex[5]);
#pragma unroll
        for (int m = 10; m < 32; ++m) dst[m] = 0;
    }
    // ---- inline reduce of round-2 partials: pef2 -> 132,133 ; per2 -> 136,137 ----
    if (t < 128) {
        int pl = t >> 2;          // node-pair 0..31 within block
        int c = t & 3;            // channel
        int p = (n0 >> 1) + pl;   // global node-pair
        float s0 = 0.f, s1 = 0.f;
        if (2 * p < N) {
            for (int ec = 0; ec < ECN; ++ec) {
                unsigned v = part2[((size_t)ec * 4 + c) * NW + p];
                s0 += blo(v);
                s1 += bhi(v);
            }
        }
        int na = 2 * p, nb = 2 * p + 1;
        float i0 = 0.f, i1 = 0.f;
        if (c < 2) {
            if (na < N) i0 = inv_fwd[na];
            if (nb < N) i1 = inv_fwd[nb];
        } else {
            if (na < N) i0 = inv_rev[na];
            if (nb < N) i1 = inv_rev[nb];
        }
        int off = (c < 2) ? (132 + c) : (134 + c);  // 132,133,136,137
        int ln = pl << 1;
        As[ln * AST + off] = f2bf(s0 * i0);
        As[(ln + 1) * AST + off] = f2bf(s1 * i1);
    }

    // ---- B frags ----
    short8 bfrag[4][5];
#pragma unroll
    for (int ct = 0; ct < 4; ++ct) {
        int c = w * 64 + ct * 16 + l15;
        const float* wcol = (c < 128) ? (W1 + (size_t)OFF_HEAD * E + c)
                                      : (W1 + (size_t)OFF_TAIL * E + (c - 128));
#pragma unroll
        for (int ks = 0; ks < 5; ++ks) {
            int kbase = ks * 32 + lg * 8;
            union { short8 v; unsigned short u[8]; } bb;
#pragma unroll
            for (int j = 0; j < 8; ++j) {
                int k = kbase + j;
                float x = (k < KTOT) ? wcol[(size_t)k * E] : 0.f;
                bb.u[j] = f2bf(x);
            }
            bfrag[ct][ks] = bb.v;
        }
    }
    __syncthreads();

    f32x4 zero = {0.f, 0.f, 0.f, 0.f};
    f32x4 acc[4][4];
#pragma unroll
    for (int rt = 0; rt < 4; ++rt)
#pragma unroll
        for (int ct = 0; ct < 4; ++ct) acc[rt][ct] = zero;

#pragma unroll
    for (int ks = 0; ks < 5; ++ks) {
        short8 afrag[4];
#pragma unroll
        for (int rt = 0; rt < 4; ++rt) {
            int row = rt * 16 + l15;
            int kb = ks * 32 + lg * 8;
            afrag[rt] = *(const short8*)&As[row * AST + kb];
        }
#pragma unroll
        for (int ct = 0; ct < 4; ++ct)
#pragma unroll
            for (int rt = 0; rt < 4; ++rt)
                acc[rt][ct] = __builtin_amdgcn_mfma_f32_16x16x32_bf16(
                    afrag[rt], bfrag[ct][ks], acc[rt][ct], 0, 0, 0);
    }

#pragma unroll
    for (int rt = 0; rt < 4; ++rt) {
#pragma unroll
        for (int ct = 0; ct < 4; ++ct) {
            int c = w * 64 + ct * 16 + l15;
            unsigned short* base = (c < 128) ? head_bf : tail_bf;
            int cc = (c < 128) ? c : c - 128;
#pragma unroll
            for (int r = 0; r < 4; ++r) {
                int node = n0 + rt * 16 + lg * 4 + r;
                if (node < N) base[(size_t)node * E + cc] = f2bf(acc[rt][ct][r]);
            }
        }
    }
}

// 16 lanes per edge, 4 edges per wave; bf16 table gathers
__global__ __launch_bounds__(256) void edge_kernel(
        const int* __restrict__ h_id, const int* __restrict__ r_id, const int* __restrict__ t_id,
        const unsigned short* __restrict__ head_bf, const unsigned short* __restrict__ rel_bf,
        const unsigned short* __restrict__ tail_bf, const float* __restrict__ bias3,
        const float* __restrict__ W2, const float* __restrict__ b2,
        float* __restrict__ out, int T) {
    int lane = threadIdx.x & 63;
    int sub = lane >> 4;
    int sl = lane & 15;
    int wid = blockIdx.x * (blockDim.x >> 6) + (threadIdx.x >> 6);
    int nw = gridDim.x * (blockDim.x >> 6);
    int c0 = sl * 8;

    float4 bi0a = *(const float4*)&bias3[c0],         bi0b = *(const float4*)&bias3[c0 + 4];
    float4 bi1a = *(const float4*)&bias3[E + c0],     bi1b = *(const float4*)&bias3[E + c0 + 4];
    float4 bi2a = *(const float4*)&bias3[2 * E + c0], bi2b = *(const float4*)&bias3[2 * E + c0 + 4];
    float4 w2a = *(const float4*)&W2[c0], w2b = *(const float4*)&W2[c0 + 4];
    float b2s = b2[0];

    int ne4 = (T + 3) >> 2;
    for (int e4 = wid; e4 < ne4; e4 += nw) {
        int e = e4 * 4 + sub;
        float p0 = 0.f, p1 = 0.f, p2 = 0.f;
        if (e < T) {
            int h = h_id[e], r = r_id[e], tt = t_id[e];
            uint4 hu = *(const uint4*)(head_bf + (size_t)h * E + c0);
            uint4 ru = *(const uint4*)(rel_bf + (size_t)r * E + c0);
            uint4 tu = *(const uint4*)(tail_bf + (size_t)tt * E + c0);
            float s[8];
            s[0] = blo(hu.x) + blo(ru.x) + blo(tu.x);
            s[1] = bhi(hu.x) + bhi(ru.x) + bhi(tu.x);
            s[2] = blo(hu.y) + blo(ru.y) + blo(tu.y);
            s[3] = bhi(hu.y) + bhi(ru.y) + bhi(tu.y);
            s[4] = blo(hu.z) + blo(ru.z) + blo(tu.z);
            s[5] = bhi(hu.z) + bhi(ru.z) + bhi(tu.z);
            s[6] = blo(hu.w) + blo(ru.w) + blo(tu.w);
            s[7] = bhi(hu.w) + bhi(ru.w) + bhi(tu.w);
            float bi0[8] = {bi0a.x, bi0a.y, bi0a.z, bi0a.w, bi0b.x, bi0b.y, bi0b.z, bi0b.w};
            float bi1[8] = {bi1a.x, bi1a.y, bi1a.z, bi1a.w, bi1b.x, bi1b.y, bi1b.z, bi1b.w};
            float bi2[8] = {bi2a.x, bi2a.y, bi2a.z, bi2a.w, bi2b.x, bi2b.y, bi2b.z, bi2b.w};
            float w2v[8] = {w2a.x, w2a.y, w2a.z, w2a.w, w2b.x, w2b.y, w2b.z, w2b.w};
#pragma unroll
            for (int j = 0; j < 8; ++j) {
                p0 = fmaf(fmaxf(s[j] + bi0[j], 0.f), w2v[j], p0);
                p1 = fmaf(fmaxf(s[j] + bi1[j], 0.f), w2v[j], p1);
                p2 = fmaf(fmaxf(s[j] + bi2[j], 0.f), w2v[j], p2);
            }
        }
#pragma unroll
        for (int o = 1; o < 16; o <<= 1) {
            p0 += __shfl_xor(p0, o, 64);
            p1 += __shfl_xor(p1, o, 64);
            p2 += __shfl_xor(p2, o, 64);
        }
        if (e < T && sl < 3) {
            float v = (sl == 0) ? p0 : ((sl == 1) ? p1 : p2);
            out[(size_t)e * 3 + sl] = v + b2s;
        }
    }
}

extern "C" void kernel_launch(void* const* d_in, const int* in_sizes, int n_in,
                              void* d_out, int out_size, void* d_ws, size_t ws_size,
                              hipStream_t stream) {
    const int* h_id = (const int*)d_in[0];
    const int* r_id = (const int*)d_in[1];
    const int* t_id = (const int*)d_in[2];
    const float* q = (const float*)d_in[3];
    const float* ent = (const float*)d_in[4];
    const float* rel = (const float*)d_in[6];
    const float* topic = (const float*)d_in[7];
    const float* nontext = (const float*)d_in[8];
    const float* intent = (const float*)d_in[9];
    const float* W1 = (const float*)d_in[10];
    const float* b1 = (const float*)d_in[11];
    const float* W2 = (const float*)d_in[12];
    const float* b2 = (const float*)d_in[13];

    int T = in_sizes[0];
    int NTEXT = in_sizes[4] / E;
    int N = in_sizes[7] / 2;
    int NREL = in_sizes[6] / E;

    float* ws = (float*)d_ws;
    float* inv_fwd = ws;                            // N
    float* inv_rev = ws + (size_t)N;                // N
    float* pef1 = ws + 2 * (size_t)N;               // 2N
    float* per1 = ws + 4 * (size_t)N;               // 2N
    float* bias3 = ws + 6 * (size_t)N;              // 3*E = 384
    unsigned* part = (unsigned*)(bias3 + 3 * E);    // ECN*6*(N/2) u32
    float* after_part = (float*)(part + (size_t)ECN * 6 * (N / 2));
    unsigned short* rel_bf = (unsigned short*)after_part;          // NREL*E bf16
    unsigned short* head_bf = rel_bf + (size_t)NREL * E;           // N*E bf16
    unsigned short* tail_bf = head_bf + (size_t)N * E;             // N*E bf16

    const int tb = 256;
    int RC1 = (N + RNG1 - 1) / RNG1;
    int RC2 = (N + RNG2 - 1) / RNG2;
    int chunk = ((T + ECN - 1) / ECN + 7) & ~7;
    int scatBlocks = RC1 * ECN;
    int relBlocks = (NREL * E + tb - 1) / tb;
    int biasBlocks = (3 * E + tb - 1) / tb;
    int NW = N / 2;

    fused1_kernel<<<scatBlocks + relBlocks + biasBlocks, tb, 0, stream>>>(
        h_id, t_id, topic, rel, intent, q, W1, b1,
        part, rel_bf, bias3, T, N, chunk, RC1, scatBlocks, relBlocks, NREL);
    reduce1_kernel<<<(NW + tb - 1) / tb, tb, 0, stream>>>(part, pef1, per1, inv_fwd, inv_rev, N);
    scat2_kernel<<<dim3(RC2, ECN), tb, 0, stream>>>(h_id, t_id, pef1, per1, part, T, N, chunk);
    nodepre_mfma<<<(N + 63) / 64, tb, 0, stream>>>(ent, nontext, topic, pef1, per1,
                                                   part, inv_fwd, inv_rev, W1,
                                                   head_bf, tail_bf, N, NTEXT);
    edge_kernel<<<2048, tb, 0, stream>>>(h_id, r_id, t_id, head_bf, rel_bf, tail_bf,
                                         bias3, W2, b2, (float*)d_out, T);
}

// Round 8
// 143.106 us; speedup vs baseline: 2.8725x; 1.1069x over previous
//
#include <hip/hip_runtime.h>

#define E 128
#define OFF_Q 128
#define OFF_HEAD 256
#define OFF_REL 394
#define OFF_TAIL 522
#define KTOT 138      // 128 + 2 + 2*4
#define KP 160
#define AST 168       // LDS A row stride in bf16 for nodepre

typedef __attribute__((ext_vector_type(8))) short short8;
typedef __attribute__((ext_vector_type(4))) float f32x4;
typedef unsigned long long u64;

#define NFIX 65536.0f
#define INV_NFIX (1.0f / 65536.0f)
#define MASK24 0xFFFFFFull

// ---- bf16 helpers (RNE, finite values only) ----
__device__ __forceinline__ unsigned short f2bf(float f) {
    unsigned u = __float_as_uint(f);
    return (unsigned short)((u + 0x7fffu + ((u >> 16) & 1u)) >> 16);
}
__device__ __forceinline__ unsigned bpack(float lo, float hi) {
    return (unsigned)f2bf(lo) | ((unsigned)f2bf(hi) << 16);
}
__device__ __forceinline__ float blo(unsigned u) { return __uint_as_float(u << 16); }
__device__ __forceinline__ float bhi(unsigned u) { return __uint_as_float(u & 0xffff0000u); }

// ---- fixed-point packed accumulator {x:24, y:24, cnt:16}, scale 2^16 ----
__device__ __forceinline__ u64 packFix(float x, float y) {
    u64 xi = (u64)__float2uint_rn(x * NFIX);
    u64 yi = (u64)__float2uint_rn(y * NFIX);
    return xi | (yi << 24) | (1ULL << 48);
}
__device__ __forceinline__ float2 unpackVal(u64 v, float scale) {
    float s = INV_NFIX * scale;
    return make_float2((float)(unsigned)(v & MASK24) * s,
                       (float)(unsigned)((v >> 24) & MASK24) * s);
}
__device__ __forceinline__ float invCnt(u64 v) {
    return 1.0f / fmaxf((float)(unsigned)(v >> 48), 1.0f);
}

// ---- fused: scat1 (packed u64 atomics) + relpre + bias + W1T transpose ----
__global__ __launch_bounds__(256) void fused1_kernel(
        const int* __restrict__ h_id, const int* __restrict__ t_id,
        const float* __restrict__ topic, const float* __restrict__ rel,
        const float* __restrict__ intent, const float* __restrict__ q,
        const float* __restrict__ W1, const float* __restrict__ b1,
        u64* __restrict__ fwd1, u64* __restrict__ rev1,
        unsigned short* __restrict__ rel_bf, float* __restrict__ bias3,
        unsigned short* __restrict__ W1T,
        int T, int scatBlocks, int relBlocks, int NREL) {
    int tid = threadIdx.x;
    int bid = blockIdx.x;

    if (bid < scatBlocks) {
        int e0 = (bid * 256 + tid) * 4;
        if (e0 < T) {
            if (e0 + 3 < T) {
                int4 h4 = *(const int4*)&h_id[e0];
                int4 t4 = *(const int4*)&t_id[e0];
                int hh[4] = {h4.x, h4.y, h4.z, h4.w};
                int tt[4] = {t4.x, t4.y, t4.z, t4.w};
#pragma unroll
                for (int j = 0; j < 4; ++j) {
                    float2 th = *(const float2*)&topic[2 * (size_t)hh[j]];
                    float2 tv = *(const float2*)&topic[2 * (size_t)tt[j]];
                    atomicAdd(&fwd1[tt[j]], packFix(th.x, th.y));
                    atomicAdd(&rev1[hh[j]], packFix(tv.x, tv.y));
                }
            } else {
                for (int e = e0; e < T; ++e) {
                    int h = h_id[e], t = t_id[e];
                    float2 th = *(const float2*)&topic[2 * (size_t)h];
                    float2 tv = *(const float2*)&topic[2 * (size_t)t];
                    atomicAdd(&fwd1[t], packFix(th.x, th.y));
                    atomicAdd(&rev1[h], packFix(tv.x, tv.y));
                }
            }
        }
    } else if (bid < scatBlocks + relBlocks) {
        // rel_bf[r][j] = rel[r]·W1[OFF_REL:][j]
        int idx = (bid - scatBlocks) * 256 + tid;
        int r = idx >> 7, j = idx & 127;
        if (r < NREL) {
            const float4* xr = (const float4*)(rel + (size_t)r * E);
            float acc = 0.f;
#pragma unroll
            for (int k4 = 0; k4 < 32; ++k4) {
                float4 x = xr[k4];
                int k = OFF_REL + k4 * 4;
                acc = fmaf(x.x, W1[(k + 0) * E + j], acc);
                acc = fmaf(x.y, W1[(k + 1) * E + j], acc);
                acc = fmaf(x.z, W1[(k + 2) * E + j], acc);
                acc = fmaf(x.w, W1[(k + 3) * E + j], acc);
            }
            rel_bf[idx] = f2bf(acc);
        }
    } else if (bid < scatBlocks + relBlocks + 2) {
        // bias3[i][j] = b1[j] + intent[i]·W1[0:128][j] + q·W1[128:256][j]
        int idx = (bid - scatBlocks - relBlocks) * 256 + tid;
        int i = idx >> 7, j = idx & 127;
        if (i < 3) {
            float acc = b1[j];
#pragma unroll 4
            for (int k = 0; k < E; ++k) acc += intent[i * E + k] * W1[k * E + j];
#pragma unroll 4
            for (int k = 0; k < E; ++k) acc += q[k] * W1[(OFF_Q + k) * E + j];
            bias3[i * E + j] = acc;
        }
    } else {
        // W1T[c][k] bf16: transposed head|tail W1 panel, K padded to 160
        int c = bid - scatBlocks - relBlocks - 2;   // 0..255
        if (tid < KP) {
            int cc = (c < 128) ? c : c - 128;
            int base = (c < 128) ? OFF_HEAD : OFF_TAIL;
            float v = (tid < KTOT) ? W1[(size_t)(base + tid) * E + cc] : 0.f;
            W1T[(size_t)c * KP + tid] = f2bf(v);
        }
    }
}

// ---- round-2 scatter: unpack round-1 on the fly, packed u64 atomics ----
__global__ __launch_bounds__(256) void scat2_kernel(
        const int* __restrict__ h_id, const int* __restrict__ t_id,
        const u64* __restrict__ fwd1, const u64* __restrict__ rev1,
        u64* __restrict__ fwd2, u64* __restrict__ rev2, int T) {
    int e0 = (blockIdx.x * 256 + threadIdx.x) * 4;
    if (e0 >= T) return;
    if (e0 + 3 < T) {
        int4 h4 = *(const int4*)&h_id[e0];
        int4 t4 = *(const int4*)&t_id[e0];
        int hh[4] = {h4.x, h4.y, h4.z, h4.w};
        int tt[4] = {t4.x, t4.y, t4.z, t4.w};
#pragma unroll
        for (int j = 0; j < 4; ++j) {
            u64 fh = fwd1[hh[j]];
            float2 p = unpackVal(fh, invCnt(fh));
            atomicAdd(&fwd2[tt[j]], packFix(p.x, p.y));
            u64 rt = rev1[tt[j]];
            float2 r = unpackVal(rt, invCnt(rt));
            atomicAdd(&rev2[hh[j]], packFix(r.x, r.y));
        }
    } else {
        for (int e = e0; e < T; ++e) {
            int h = h_id[e], t = t_id[e];
            u64 fh = fwd1[h];
            float2 p = unpackVal(fh, invCnt(fh));
            atomicAdd(&fwd2[t], packFix(p.x, p.y));
            u64 rt = rev1[t];
            float2 r = unpackVal(rt, invCnt(rt));
            atomicAdd(&rev2[h], packFix(r.x, r.y));
        }
    }
}

// ---- head/tail precompute via MFMA, B from bf16 W1T (L2-hot) ----
__global__ __launch_bounds__(256) void nodepre_mfma(
        const float* __restrict__ ent, const float* __restrict__ nontext,
        const float* __restrict__ topic,
        const u64* __restrict__ fwd1, const u64* __restrict__ rev1,
        const u64* __restrict__ fwd2, const u64* __restrict__ rev2,
        const unsigned short* __restrict__ W1T,
        unsigned short* __restrict__ head_bf, unsigned short* __restrict__ tail_bf,
        int N, int NTEXT) {
    __shared__ unsigned short As[64 * AST];
    int t = threadIdx.x;
    int lane = t & 63;
    int w = t >> 6;
    int l15 = lane & 15;
    int lg = lane >> 4;
    int n0 = blockIdx.x * 64;

    // stage A rows (k<128)
    {
        int row = t >> 2, ch = t & 3;
        int node = n0 + row;
        bool ok = node < N;
        const float* src = (node < NTEXT) ? (ent + (size_t)node * E) : nontext;
        unsigned* dst = (unsigned*)&As[row * AST + ch * 32];
#pragma unroll
        for (int qq = 0; qq < 8; ++qq) {
            float4 v = ok ? *(const float4*)(src + ch * 32 + qq * 4)
                          : make_float4(0.f, 0.f, 0.f, 0.f);
            dst[qq * 2 + 0] = bpack(v.x, v.y);
            dst[qq * 2 + 1] = bpack(v.z, v.w);
        }
    }
    // extras k=128..137: topic, pef1, pef2, per1, per2 (unpacked inline)
    if (t < 64) {
        int node = n0 + t;
        bool ok = node < N;
        unsigned short* dst = &As[t * AST + 128];
        float2 tp = make_float2(0.f, 0.f), p1 = tp, p2 = tp, q1 = tp, q2 = tp;
        if (ok) {
            tp = *(const float2*)&topic[2 * (size_t)node];
            u64 f1v = fwd1[node], r1v = rev1[node];
            u64 f2v = fwd2[node], r2v = rev2[node];
            float invf = invCnt(f1v), invr = invCnt(r1v);
            p1 = unpackVal(f1v, invf);
            p2 = unpackVal(f2v, invf);
            q1 = unpackVal(r1v, invr);
            q2 = unpackVal(r2v, invr);
        }
        dst[0] = f2bf(tp.x); dst[1] = f2bf(tp.y);
        dst[2] = f2bf(p1.x); dst[3] = f2bf(p1.y);
        dst[4] = f2bf(p2.x); dst[5] = f2bf(p2.y);
        dst[6] = f2bf(q1.x); dst[7] = f2bf(q1.y);
        dst[8] = f2bf(q2.x); dst[9] = f2bf(q2.y);
#pragma unroll
        for (int m = 10; m < 32; ++m) dst[m] = 0;
    }
    __syncthreads();

    f32x4 zero = {0.f, 0.f, 0.f, 0.f};
    f32x4 acc[4][4];
#pragma unroll
    for (int rt = 0; rt < 4; ++rt)
#pragma unroll
        for (int ct = 0; ct < 4; ++ct) acc[rt][ct] = zero;

#pragma unroll
    for (int ks = 0; ks < 5; ++ks) {
        int kb = ks * 32 + lg * 8;
        short8 afrag[4];
#pragma unroll
        for (int rt = 0; rt < 4; ++rt)
            afrag[rt] = *(const short8*)&As[(rt * 16 + l15) * AST + kb];
#pragma unroll
        for (int ct = 0; ct < 4; ++ct) {
            int c = w * 64 + ct * 16 + l15;
            short8 b = *(const short8*)&W1T[(size_t)c * KP + kb];
#pragma unroll
            for (int rt = 0; rt < 4; ++rt)
                acc[rt][ct] = __builtin_amdgcn_mfma_f32_16x16x32_bf16(
                    afrag[rt], b, acc[rt][ct], 0, 0, 0);
        }
    }

#pragma unroll
    for (int rt = 0; rt < 4; ++rt) {
#pragma unroll
        for (int ct = 0; ct < 4; ++ct) {
            int c = w * 64 + ct * 16 + l15;
            unsigned short* base = (c < 128) ? head_bf : tail_bf;
            int cc = (c < 128) ? c : c - 128;
#pragma unroll
            for (int r = 0; r < 4; ++r) {
                int node = n0 + rt * 16 + lg * 4 + r;
                if (node < N) base[(size_t)node * E + cc] = f2bf(acc[rt][ct][r]);
            }
        }
    }
}

// 16 lanes per edge, 4 edges per wave; bf16 table gathers
__global__ __launch_bounds__(256) void edge_kernel(
        const int* __restrict__ h_id, const int* __restrict__ r_id, const int* __restrict__ t_id,
        const unsigned short* __restrict__ head_bf, const unsigned short* __restrict__ rel_bf,
        const unsigned short* __restrict__ tail_bf, const float* __restrict__ bias3,
        const float* __restrict__ W2, const float* __restrict__ b2,
        float* __restrict__ out, int T) {
    int lane = threadIdx.x & 63;
    int sub = lane >> 4;
    int sl = lane & 15;
    int wid = blockIdx.x * (blockDim.x >> 6) + (threadIdx.x >> 6);
    int nw = gridDim.x * (blockDim.x >> 6);
    int c0 = sl * 8;

    float4 bi0a = *(const float4*)&bias3[c0],         bi0b = *(const float4*)&bias3[c0 + 4];
    float4 bi1a = *(const float4*)&bias3[E + c0],     bi1b = *(const float4*)&bias3[E + c0 + 4];
    float4 bi2a = *(const float4*)&bias3[2 * E + c0], bi2b = *(const float4*)&bias3[2 * E + c0 + 4];
    float4 w2a = *(const float4*)&W2[c0], w2b = *(const float4*)&W2[c0 + 4];
    float b2s = b2[0];

    int ne4 = (T + 3) >> 2;
    for (int e4 = wid; e4 < ne4; e4 += nw) {
        int e = e4 * 4 + sub;
        float p0 = 0.f, p1 = 0.f, p2 = 0.f;
        if (e < T) {
            int h = h_id[e], r = r_id[e], tt = t_id[e];
            uint4 hu = *(const uint4*)(head_bf + (size_t)h * E + c0);
            uint4 ru = *(const uint4*)(rel_bf + (size_t)r * E + c0);
            uint4 tu = *(const uint4*)(tail_bf + (size_t)tt * E + c0);
            float s[8];
            s[0] = blo(hu.x) + blo(ru.x) + blo(tu.x);
            s[1] = bhi(hu.x) + bhi(ru.x) + bhi(tu.x);
            s[2] = blo(hu.y) + blo(ru.y) + blo(tu.y);
            s[3] = bhi(hu.y) + bhi(ru.y) + bhi(tu.y);
            s[4] = blo(hu.z) + blo(ru.z) + blo(tu.z);
            s[5] = bhi(hu.z) + bhi(ru.z) + bhi(tu.z);
            s[6] = blo(hu.w) + blo(ru.w) + blo(tu.w);
            s[7] = bhi(hu.w) + bhi(ru.w) + bhi(tu.w);
            float bi0[8] = {bi0a.x, bi0a.y, bi0a.z, bi0a.w, bi0b.x, bi0b.y, bi0b.z, bi0b.w};
            float bi1[8] = {bi1a.x, bi1a.y, bi1a.z, bi1a.w, bi1b.x, bi1b.y, bi1b.z, bi1b.w};
            float bi2[8] = {bi2a.x, bi2a.y, bi2a.z, bi2a.w, bi2b.x, bi2b.y, bi2b.z, bi2b.w};
            float w2v[8] = {w2a.x, w2a.y, w2a.z, w2a.w, w2b.x, w2b.y, w2b.z, w2b.w};
#pragma unroll
            for (int j = 0; j < 8; ++j) {
                p0 = fmaf(fmaxf(s[j] + bi0[j], 0.f), w2v[j], p0);
                p1 = fmaf(fmaxf(s[j] + bi1[j], 0.f), w2v[j], p1);
                p2 = fmaf(fmaxf(s[j] + bi2[j], 0.f), w2v[j], p2);
            }
        }
#pragma unroll
        for (int o = 1; o < 16; o <<= 1) {
            p0 += __shfl_xor(p0, o, 64);
            p1 += __shfl_xor(p1, o, 64);
            p2 += __shfl_xor(p2, o, 64);
        }
        if (e < T && sl < 3) {
            float v = (sl == 0) ? p0 : ((sl == 1) ? p1 : p2);
            out[(size_t)e * 3 + sl] = v + b2s;
        }
    }
}

extern "C" void kernel_launch(void* const* d_in, const int* in_sizes, int n_in,
                              void* d_out, int out_size, void* d_ws, size_t ws_size,
                              hipStream_t stream) {
    const int* h_id = (const int*)d_in[0];
    const int* r_id = (const int*)d_in[1];
    const int* t_id = (const int*)d_in[2];
    const float* q = (const float*)d_in[3];
    const float* ent = (const float*)d_in[4];
    const float* rel = (const float*)d_in[6];
    const float* topic = (const float*)d_in[7];
    const float* nontext = (const float*)d_in[8];
    const float* intent = (const float*)d_in[9];
    const float* W1 = (const float*)d_in[10];
    const float* b1 = (const float*)d_in[11];
    const float* W2 = (const float*)d_in[12];
    const float* b2 = (const float*)d_in[13];

    int T = in_sizes[0];
    int NTEXT = in_sizes[4] / E;
    int N = in_sizes[7] / 2;
    int NREL = in_sizes[6] / E;

    u64* fwd1 = (u64*)d_ws;                         // N
    u64* rev1 = fwd1 + N;                           // N
    u64* fwd2 = rev1 + N;                           // N
    u64* rev2 = fwd2 + N;                           // N
    float* bias3 = (float*)(rev2 + N);              // 3*E
    unsigned short* W1T = (unsigned short*)(bias3 + 3 * E);        // 256*160
    unsigned short* rel_bf = W1T + 256 * KP;                       // NREL*E
    unsigned short* head_bf = rel_bf + (size_t)NREL * E;           // N*E
    unsigned short* tail_bf = head_bf + (size_t)N * E;             // N*E

    const int tb = 256;
    int scatBlocks = (T + tb * 4 - 1) / (tb * 4);
    int relBlocks = (NREL * E + tb - 1) / tb;

    hipMemsetAsync(d_ws, 0, sizeof(u64) * 4 * (size_t)N, stream);

    fused1_kernel<<<scatBlocks + relBlocks + 2 + 256, tb, 0, stream>>>(
        h_id, t_id, topic, rel, intent, q, W1, b1,
        fwd1, rev1, rel_bf, bias3, W1T, T, scatBlocks, relBlocks, NREL);
    scat2_kernel<<<scatBlocks, tb, 0, stream>>>(h_id, t_id, fwd1, rev1, fwd2, rev2, T);
    nodepre_mfma<<<(N + 63) / 64, tb, 0, stream>>>(ent, nontext, topic,
                                                   fwd1, rev1, fwd2, rev2, W1T,
                                                   head_bf, tail_bf, N, NTEXT);
    edge_kernel<<<2048, tb, 0, stream>>>(h_id, r_id, t_id, head_bf, rel_bf, tail_bf,
                                         bias3, W2, b2, (float*)d_out, T);
}